// Round 1
// baseline (1396.478 us; speedup 1.0000x reference)
//
#include <hip/hip_runtime.h>
#include <cstddef>

// Problem constants
#define BSZ   2
#define NSEQ  2048
#define NROWS 4096        // B*N
#define HIDD  128
#define NH    8
#define VD    16
#define ATT_S 16          // j-splits for attention
#define ATT_JS (NSEQ/ATT_S)

__device__ __forceinline__ float gelu_f(float x) {
    // exact (erf) gelu, matching jax.nn.gelu(approximate=False) in fp32
    return 0.5f * x * (1.0f + erff(x * 0.70710678118654752440f));
}

// ---------------------------------------------------------------------------
// Per-row 5th-percentile support: sort each m_dist row (2048) and emit the
// 103rd/104th smallest (0-indexed ranks 102,103). Bitonic sort in LDS.
// ---------------------------------------------------------------------------
__global__ __launch_bounds__(256) void percentile_kernel(
    const float* __restrict__ m, float* __restrict__ m102, float* __restrict__ m103)
{
    __shared__ float s[2048];
    const int row = blockIdx.x;               // 0..4095 = b*2048+n
    const float* mr = m + (size_t)row * 2048;
    for (int i = threadIdx.x; i < 2048; i += 256) s[i] = mr[i];
    __syncthreads();
    for (int k = 2; k <= 2048; k <<= 1) {
        for (int j = k >> 1; j > 0; j >>= 1) {
            for (int i = threadIdx.x; i < 2048; i += 256) {
                int ixj = i ^ j;
                if (ixj > i) {
                    float a = s[i], b = s[ixj];
                    bool up = ((i & k) == 0);
                    if ((a > b) == up) { s[i] = b; s[ixj] = a; }
                }
            }
            __syncthreads();
        }
    }
    if (threadIdx.x == 0) { m102[row] = s[102]; m103[row] = s[103]; }
}

// ---------------------------------------------------------------------------
// Encoder: en = gelu(inputs(4096,3) @ W(3,128) + b)
// ---------------------------------------------------------------------------
__global__ __launch_bounds__(256) void encoder_kernel(
    const float* __restrict__ inp, const float* __restrict__ W,
    const float* __restrict__ b, float* __restrict__ out)
{
    int idx = blockIdx.x * 256 + threadIdx.x;   // 4096*128
    int row = idx >> 7, c = idx & 127;
    float x0 = inp[row * 3 + 0], x1 = inp[row * 3 + 1], x2 = inp[row * 3 + 2];
    float y = x0 * W[c] + x1 * W[128 + c] + x2 * W[256 + c] + b[c];
    out[idx] = gelu_f(y);
}

// ---------------------------------------------------------------------------
// Generic (4096,128) @ (128,128) matmul, W staged in LDS.
// vw_layout: W element (k,c) comes from w[(c>>4)*2048 + k*16 + (c&15)]
//            (reorders (H,HID,VD) head weights into a single (128,128) W).
// bias / addsrc nullable; optional gelu.
// ---------------------------------------------------------------------------
__global__ __launch_bounds__(256) void matmul128_kernel(
    const float* __restrict__ X, const float* __restrict__ W,
    const float* __restrict__ bias, const float* __restrict__ addsrc,
    float* __restrict__ out, int vw_layout, int do_gelu)
{
    __shared__ float Ws[128][128];   // 64 KB
    __shared__ float Xs[16][132];    // padded stride (132%4==0 keeps f4 align)
    const int t = threadIdx.x;
    const int row0 = blockIdx.x * 16;

    if (vw_layout) {
        for (int i = t; i < 16384; i += 256) {
            int k = i >> 7, c = i & 127;
            Ws[k][c] = W[((size_t)(c >> 4) << 11) + (k << 4) + (c & 15)];
        }
    } else {
        for (int i = t; i < 16384; i += 256) {
            Ws[i >> 7][i & 127] = W[i];
        }
    }
    for (int i = t; i < 16 * 32; i += 256) {
        int r = i >> 5, kk = (i & 31) << 2;
        float4 xv = *(const float4*)(X + (size_t)(row0 + r) * 128 + kk);
        *(float4*)&Xs[r][kk] = xv;
    }
    __syncthreads();

    const int cg = t & 31, rg = t >> 5;   // 32 col-groups x 8 row-groups
    const int c0 = cg << 2;
    const int r0 = rg << 1;               // 2 rows per thread -> 16 rows/block
    float acc[2][4] = {{0.f,0.f,0.f,0.f},{0.f,0.f,0.f,0.f}};

    for (int k = 0; k < 128; k += 4) {
        float4 xa = *(const float4*)&Xs[r0][k];
        float4 xb = *(const float4*)&Xs[r0 + 1][k];
        float xav[4] = {xa.x, xa.y, xa.z, xa.w};
        float xbv[4] = {xb.x, xb.y, xb.z, xb.w};
        #pragma unroll
        for (int kk = 0; kk < 4; ++kk) {
            float4 wv = *(const float4*)&Ws[k + kk][c0];
            acc[0][0] += xav[kk] * wv.x; acc[0][1] += xav[kk] * wv.y;
            acc[0][2] += xav[kk] * wv.z; acc[0][3] += xav[kk] * wv.w;
            acc[1][0] += xbv[kk] * wv.x; acc[1][1] += xbv[kk] * wv.y;
            acc[1][2] += xbv[kk] * wv.z; acc[1][3] += xbv[kk] * wv.w;
        }
    }

    #pragma unroll
    for (int i = 0; i < 2; ++i) {
        int r = row0 + r0 + i;
        float4 y;
        float* yp = (float*)&y;
        #pragma unroll
        for (int d = 0; d < 4; ++d) {
            float v = acc[i][d];
            if (bias)   v += bias[c0 + d];
            if (addsrc) v += addsrc[(size_t)r * 128 + c0 + d];
            if (do_gelu) v = gelu_f(v);
            yp[d] = v;
        }
        *(float4*)(out + (size_t)r * 128 + c0) = y;
    }
}

// ---------------------------------------------------------------------------
// Attention partial pass. One wave (64 threads) per block.
// Lane l: h = l>>3 (owns one head -> exp computed with zero redundancy),
//         ng = l&7; rows row0 = rg*16+ng, row1 = row0+8 (16 rows per wave).
// j is split ATT_S ways across blocks; partial (acc, wsum) written to ws.
// ---------------------------------------------------------------------------
__global__ __launch_bounds__(64) void attn_kernel(
    const float* __restrict__ m_dist,   // (B,N,N)
    const float* __restrict__ v,        // (B,N,128), c = h*16+d
    const float* __restrict__ rvec,     // 8 floats (head radii)
    const float* __restrict__ m102, const float* __restrict__ m103,
    float* __restrict__ part,           // (ATT_S, 4096, 128)
    float* __restrict__ wsum,           // (ATT_S, 4096, 8)
    int masked)
{
    const int blk = blockIdx.x;
    const int s  = blk & (ATT_S - 1);
    const int rg = blk >> 4;            // 0..255
    const int l  = threadIdx.x;
    const int h  = l >> 3, ng = l & 7;
    const int row0 = rg * 16 + ng;
    const int row1 = row0 + 8;
    const int b  = row0 >> 11;
    const int n0 = row0 & 2047, n1 = row1 & 2047;

    const float r  = rvec[h];
    const float r2 = r * r;

    float thr0 = 3.4028235e38f, thr1 = 3.4028235e38f;
    if (masked) {
        // replicate tfp linear-percentile interpolation bit-for-bit:
        // pos = 5/100*(N-1); frac = float32(pos - floor(pos))
        const double pos = 5.0 / 100.0 * 2047.0;
        const float FRAC = (float)(pos - 102.0);
        const float OM   = 1.0f - FRAC;
        thr0 = (m102[row0] * r2) * OM + (m103[row0] * r2) * FRAC;
        thr1 = (m102[row1] * r2) * OM + (m103[row1] * r2) * FRAC;
    }

    const float* mrow0 = m_dist + ((size_t)b << 22) + ((size_t)n0 << 11);
    const float* mrow1 = m_dist + ((size_t)b << 22) + ((size_t)n1 << 11);
    const float* vb    = v + ((size_t)b << 18) + (h << 4);

    float acc0[16], acc1[16];
    #pragma unroll
    for (int d = 0; d < 16; ++d) { acc0[d] = 0.f; acc1[d] = 0.f; }
    float ws0 = 0.f, ws1 = 0.f;

    const int j0 = s * ATT_JS;
    for (int j = j0; j < j0 + ATT_JS; ++j) {
        float m0 = mrow0[j], m1 = mrow1[j];
        float sd0 = m0 * r2, sd1 = m1 * r2;
        float w0 = (sd0 <= thr0) ? __expf(-sd0) : 0.f;
        float w1 = (sd1 <= thr1) ? __expf(-sd1) : 0.f;
        ws0 += w0; ws1 += w1;
        const float4* vp = (const float4*)(vb + ((size_t)j << 7));
        float va[16];
        *(float4*)(va)      = vp[0];
        *(float4*)(va + 4)  = vp[1];
        *(float4*)(va + 8)  = vp[2];
        *(float4*)(va + 12) = vp[3];
        #pragma unroll
        for (int d = 0; d < 16; ++d) {
            acc0[d] += w0 * va[d];
            acc1[d] += w1 * va[d];
        }
    }

    size_t po0 = (((size_t)s * 4096 + row0) << 7) + (h << 4);
    size_t po1 = (((size_t)s * 4096 + row1) << 7) + (h << 4);
    float4* p0 = (float4*)(part + po0);
    float4* p1 = (float4*)(part + po1);
    p0[0] = make_float4(acc0[0], acc0[1], acc0[2], acc0[3]);
    p0[1] = make_float4(acc0[4], acc0[5], acc0[6], acc0[7]);
    p0[2] = make_float4(acc0[8], acc0[9], acc0[10], acc0[11]);
    p0[3] = make_float4(acc0[12], acc0[13], acc0[14], acc0[15]);
    p1[0] = make_float4(acc1[0], acc1[1], acc1[2], acc1[3]);
    p1[1] = make_float4(acc1[4], acc1[5], acc1[6], acc1[7]);
    p1[2] = make_float4(acc1[8], acc1[9], acc1[10], acc1[11]);
    p1[3] = make_float4(acc1[12], acc1[13], acc1[14], acc1[15]);
    wsum[((size_t)s * 4096 + row0) * 8 + h] = ws0;
    wsum[((size_t)s * 4096 + row1) * 8 + h] = ws1;
}

// Combine partials: out = gelu( sum_s acc / sum_s wsum )
__global__ __launch_bounds__(256) void attn_combine_kernel(
    const float* __restrict__ part, const float* __restrict__ wsum,
    float* __restrict__ out)
{
    int idx = blockIdx.x * 256 + threadIdx.x;   // 4096*128
    int row = idx >> 7, c = idx & 127, h = c >> 4;
    float a = 0.f, w = 0.f;
    #pragma unroll
    for (int s = 0; s < ATT_S; ++s) {
        a += part[((size_t)s * 4096 + row) * 128 + c];
        w += wsum[((size_t)s * 4096 + row) * 8 + h];
    }
    out[idx] = gelu_f(a / w);
}

// Final projection: out(4096,1) = t6(4096,128) @ W(128,1) + b
__global__ __launch_bounds__(256) void final_kernel(
    const float* __restrict__ X, const float* __restrict__ W,
    const float* __restrict__ b, float* __restrict__ out)
{
    int row = blockIdx.x * 256 + threadIdx.x;   // 4096
    const float4* x = (const float4*)(X + (size_t)row * 128);
    float acc = 0.f;
    #pragma unroll
    for (int k4 = 0; k4 < 32; ++k4) {
        float4 xv = x[k4];
        float4 wv = *(const float4*)(W + k4 * 4);
        acc += xv.x * wv.x + xv.y * wv.y + xv.z * wv.z + xv.w * wv.w;
    }
    out[row] = acc + b[0];
}

// ---------------------------------------------------------------------------
extern "C" void kernel_launch(void* const* d_in, const int* in_sizes, int n_in,
                              void* d_out, int out_size, void* d_ws, size_t ws_size,
                              hipStream_t stream)
{
    (void)in_sizes; (void)n_in; (void)out_size; (void)ws_size;
    const float* m_dist  = (const float*)d_in[0];
    const float* inputs  = (const float*)d_in[1];
    const float* en_W    = (const float*)d_in[2];
    const float* en_b    = (const float*)d_in[3];
    const float* down_r  = (const float*)d_in[4];
    const float* down_w  = (const float*)d_in[5];
    const float* mlp1_W1 = (const float*)d_in[6];
    const float* mlp1_b1 = (const float*)d_in[7];
    const float* mlp1_W2 = (const float*)d_in[8];
    const float* mlp1_b2 = (const float*)d_in[9];
    const float* w1_W    = (const float*)d_in[10];
    const float* w1_b    = (const float*)d_in[11];
    const float* pa_r    = (const float*)d_in[12];
    const float* pa_w    = (const float*)d_in[13];
    const float* blk_W1  = (const float*)d_in[14];
    const float* blk_b1  = (const float*)d_in[15];
    const float* blk_W2  = (const float*)d_in[16];
    const float* blk_b2  = (const float*)d_in[17];
    const float* wi_W    = (const float*)d_in[18];
    const float* wi_b    = (const float*)d_in[19];
    const float* up_r    = (const float*)d_in[20];
    const float* up_w    = (const float*)d_in[21];
    const float* mlp2_W1 = (const float*)d_in[22];
    const float* mlp2_b1 = (const float*)d_in[23];
    const float* mlp2_W2 = (const float*)d_in[24];
    const float* mlp2_b2 = (const float*)d_in[25];
    const float* w2_W    = (const float*)d_in[26];
    const float* w2_b    = (const float*)d_in[27];
    const float* de_W1   = (const float*)d_in[28];
    const float* de_b1   = (const float*)d_in[29];
    const float* de_W2   = (const float*)d_in[30];
    const float* de_b2   = (const float*)d_in[31];
    float* out = (float*)d_out;

    // workspace layout (floats); total ~50.4 MB
    const size_t BUF = (size_t)NROWS * HIDD;   // 524288
    float* w     = (float*)d_ws;
    float* ben   = w;
    float* bx0   = w + 1 * BUF;
    float* bx1   = w + 2 * BUF;
    float* bt    = w + 3 * BUF;
    float* bh    = w + 4 * BUF;
    float* br    = w + 5 * BUF;
    float* bv    = w + 6 * BUF;
    float* m102  = w + 7 * BUF;
    float* m103  = m102 + NROWS;
    float* part  = m103 + NROWS;                       // ATT_S*4096*128
    float* wsumb = part + (size_t)ATT_S * NROWS * HIDD; // ATT_S*4096*8

    dim3 b256(256), b64(64);
    dim3 gElem((NROWS * HIDD) / 256);   // 2048
    dim3 gMM(NROWS / 16);               // 256
    dim3 gAtt(256 * ATT_S);             // 4096

    auto mm = [&](const float* X, const float* Wm, const float* bias,
                  const float* add, float* o, int vw, int g) {
        matmul128_kernel<<<gMM, b256, 0, stream>>>(X, Wm, bias, add, o, vw, g);
    };
    auto attn = [&](const float* x, const float* wv, const float* rv,
                    int masked, float* o) {
        mm(x, wv, nullptr, nullptr, bv, 1, 0);
        attn_kernel<<<gAtt, b64, 0, stream>>>(m_dist, bv, rv, m102, m103,
                                              part, wsumb, masked);
        attn_combine_kernel<<<gElem, b256, 0, stream>>>(part, wsumb, o);
    };

    // percentile thresholds (used by both masked mhpas)
    percentile_kernel<<<dim3(NROWS), b256, 0, stream>>>(m_dist, m102, m103);

    // encoder
    encoder_kernel<<<gElem, b256, 0, stream>>>(inputs, en_W, en_b, ben);

    // down block: x = gelu(mlp(mhpa(en, down, loc=5)) + en@w1_W + w1_b)
    attn(ben, down_w, down_r, 1, bh);
    mm(bh, mlp1_W1, mlp1_b1, nullptr, bt, 0, 1);
    mm(ben, w1_W, w1_b, nullptr, br, 0, 0);
    mm(bt, mlp1_W2, mlp1_b2, br, bx0, 0, 1);

    // 4 processor blocks (ping-pong x between bx0/bx1)
    float* xin = bx0;
    float* xout = bx1;
    for (int i = 0; i < 4; ++i) {
        attn(xin, pa_w + (size_t)i * NH * HIDD * VD, pa_r + (size_t)i * NH, 0, bh);
        mm(bh, blk_W1 + (size_t)i * HIDD * HIDD, blk_b1 + (size_t)i * HIDD,
           nullptr, bt, 0, 1);
        mm(xin, wi_W + (size_t)i * HIDD * HIDD, wi_b + (size_t)i * HIDD,
           nullptr, br, 0, 0);
        mm(bt, blk_W2 + (size_t)i * HIDD * HIDD, blk_b2 + (size_t)i * HIDD,
           br, xout, 0, 1);
        float* tmp = xin; xin = xout; xout = tmp;
    }
    // xin now holds x (== bx0 after 4 swaps)

    // up block: de = gelu(mlp(mhpa(x, up, loc=5)) + x@w2_W + w2_b)
    attn(xin, up_w, up_r, 1, bh);
    mm(bh, mlp2_W1, mlp2_b1, nullptr, bt, 0, 1);
    mm(xin, w2_W, w2_b, nullptr, br, 0, 0);
    mm(bt, mlp2_W2, mlp2_b2, br, xout, 0, 1);   // de -> xout (bx1)

    // decoder mlp
    mm(xout, de_W1, de_b1, nullptr, bt, 0, 1);
    final_kernel<<<dim3(NROWS / 256), b256, 0, stream>>>(bt, de_W2, de_b2, out);
}

// Round 2
// 1057.248 us; speedup vs baseline: 1.3209x; 1.3209x over previous
//
#include <hip/hip_runtime.h>
#include <cstddef>

// Problem constants
#define BSZ   2
#define NSEQ  2048
#define NROWS 4096        // B*N
#define HIDD  128
#define NH    8
#define VD    16
#define ATT_S 16          // j-splits for attention
#define ATT_JS (NSEQ/ATT_S)

__device__ __forceinline__ float gelu_f(float x) {
    // exact (erf) gelu, matching jax.nn.gelu(approximate=False) in fp32
    return 0.5f * x * (1.0f + erff(x * 0.70710678118654752440f));
}

// ---------------------------------------------------------------------------
// Per-row 5th-percentile support: emit the elements of sorted rank 102 and 103
// (0-indexed) of each m_dist row. Histogram select: 256 uniform bins over
// [0,1), wave-scan cumulative counts, collect the ~16 elements living in the
// rank-102/103 bins, exact rank by counting. 4 barriers total (the old
// bitonic sort had 66 and cost 208 us).
// ---------------------------------------------------------------------------
__global__ __launch_bounds__(256) void percentile_kernel(
    const float* __restrict__ m, float* __restrict__ m102, float* __restrict__ m103)
{
    __shared__ int   cnt[256];
    __shared__ int   cum[256];
    __shared__ float buf[192];
    __shared__ int   nc;
    __shared__ int   sb0, sb1, sbase;

    const int row = blockIdx.x;               // 0..4095 = b*2048+n
    const int t   = threadIdx.x;
    const float* mr = m + (size_t)row * 2048;

    float4 a = *(const float4*)(mr + t * 8);
    float4 c = *(const float4*)(mr + t * 8 + 4);
    float v[8] = {a.x, a.y, a.z, a.w, c.x, c.y, c.z, c.w};

    cnt[t] = 0;
    if (t == 0) nc = 0;
    __syncthreads();

    int bidx[8];
    #pragma unroll
    for (int i = 0; i < 8; ++i) {
        int bi = (int)(v[i] * 256.0f);
        bi = bi < 0 ? 0 : (bi > 255 ? 255 : bi);
        bidx[i] = bi;
        atomicAdd(&cnt[bi], 1);
    }
    __syncthreads();

    // inclusive prefix over 256 bins, done by wave 0 (4 bins/lane + shfl scan)
    if (t < 64) {
        int c0 = cnt[t * 4], c1 = cnt[t * 4 + 1], c2 = cnt[t * 4 + 2], c3 = cnt[t * 4 + 3];
        int s1 = c0 + c1, s2 = s1 + c2, s3 = s2 + c3;
        int sc = s3;
        #pragma unroll
        for (int off = 1; off < 64; off <<= 1) {
            int o = __shfl_up(sc, off);
            if (t >= off) sc += o;
        }
        int base = sc - s3;
        cum[t * 4]     = base + c0;
        cum[t * 4 + 1] = base + s1;
        cum[t * 4 + 2] = base + s2;
        cum[t * 4 + 3] = base + s3;
    }
    __syncthreads();

    {   // find the bins holding ranks 102 and 103 (exactly one thread each)
        int cprev = (t == 0) ? 0 : cum[t - 1];
        int cthis = cum[t];
        if (cprev < 103 && 103 <= cthis) { sb0 = t; sbase = cprev; }
        if (cprev < 104 && 104 <= cthis) { sb1 = t; }
    }
    __syncthreads();

    const int b0 = sb0, b1 = sb1, base = sbase;
    #pragma unroll
    for (int i = 0; i < 8; ++i) {
        if (bidx[i] >= b0 && bidx[i] <= b1) {
            int p = atomicAdd(&nc, 1);
            if (p < 192) buf[p] = v[i];
        }
    }
    __syncthreads();

    int n = nc; if (n > 192) n = 192;
    if (t < n) {
        float x = buf[t];
        int rk = base;
        for (int j = 0; j < n; ++j) {
            float y = buf[j];
            rk += (y < x || (y == x && j < t)) ? 1 : 0;
        }
        if (rk == 102) m102[row] = x;
        if (rk == 103) m103[row] = x;
    }
}

// ---------------------------------------------------------------------------
// Encoder: en = gelu(inputs(4096,3) @ W(3,128) + b)
// ---------------------------------------------------------------------------
__global__ __launch_bounds__(256) void encoder_kernel(
    const float* __restrict__ inp, const float* __restrict__ W,
    const float* __restrict__ b, float* __restrict__ out)
{
    int idx = blockIdx.x * 256 + threadIdx.x;   // 4096*128
    int row = idx >> 7, c = idx & 127;
    float x0 = inp[row * 3 + 0], x1 = inp[row * 3 + 1], x2 = inp[row * 3 + 2];
    float y = x0 * W[c] + x1 * W[128 + c] + x2 * W[256 + c] + b[c];
    out[idx] = gelu_f(y);
}

// ---------------------------------------------------------------------------
// Generic (4096,128) @ (128,128) matmul, W staged in LDS.
// vw_layout: W element (k,c) comes from w[(c>>4)*2048 + k*16 + (c&15)]
//            (reorders (H,HID,VD) head weights into a single (128,128) W).
// bias / addsrc nullable; optional gelu.
// ---------------------------------------------------------------------------
__global__ __launch_bounds__(256) void matmul128_kernel(
    const float* __restrict__ X, const float* __restrict__ W,
    const float* __restrict__ bias, const float* __restrict__ addsrc,
    float* __restrict__ out, int vw_layout, int do_gelu)
{
    __shared__ float Ws[128][128];   // 64 KB
    __shared__ float Xs[16][132];    // padded stride (132%4==0 keeps f4 align)
    const int t = threadIdx.x;
    const int row0 = blockIdx.x * 16;

    if (vw_layout) {
        for (int i = t; i < 16384; i += 256) {
            int k = i >> 7, c = i & 127;
            Ws[k][c] = W[((size_t)(c >> 4) << 11) + (k << 4) + (c & 15)];
        }
    } else {
        for (int i = t; i < 16384; i += 256) {
            Ws[i >> 7][i & 127] = W[i];
        }
    }
    for (int i = t; i < 16 * 32; i += 256) {
        int r = i >> 5, kk = (i & 31) << 2;
        float4 xv = *(const float4*)(X + (size_t)(row0 + r) * 128 + kk);
        *(float4*)&Xs[r][kk] = xv;
    }
    __syncthreads();

    const int cg = t & 31, rg = t >> 5;   // 32 col-groups x 8 row-groups
    const int c0 = cg << 2;
    const int r0 = rg << 1;               // 2 rows per thread -> 16 rows/block
    float acc[2][4] = {{0.f,0.f,0.f,0.f},{0.f,0.f,0.f,0.f}};

    for (int k = 0; k < 128; k += 4) {
        float4 xa = *(const float4*)&Xs[r0][k];
        float4 xb = *(const float4*)&Xs[r0 + 1][k];
        float xav[4] = {xa.x, xa.y, xa.z, xa.w};
        float xbv[4] = {xb.x, xb.y, xb.z, xb.w};
        #pragma unroll
        for (int kk = 0; kk < 4; ++kk) {
            float4 wv = *(const float4*)&Ws[k + kk][c0];
            acc[0][0] += xav[kk] * wv.x; acc[0][1] += xav[kk] * wv.y;
            acc[0][2] += xav[kk] * wv.z; acc[0][3] += xav[kk] * wv.w;
            acc[1][0] += xbv[kk] * wv.x; acc[1][1] += xbv[kk] * wv.y;
            acc[1][2] += xbv[kk] * wv.z; acc[1][3] += xbv[kk] * wv.w;
        }
    }

    #pragma unroll
    for (int i = 0; i < 2; ++i) {
        int r = row0 + r0 + i;
        float4 y;
        float* yp = (float*)&y;
        #pragma unroll
        for (int d = 0; d < 4; ++d) {
            float v = acc[i][d];
            if (bias)   v += bias[c0 + d];
            if (addsrc) v += addsrc[(size_t)r * 128 + c0 + d];
            if (do_gelu) v = gelu_f(v);
            yp[d] = v;
        }
        *(float4*)(out + (size_t)r * 128 + c0) = y;
    }
}

// ---------------------------------------------------------------------------
// Attention partial pass. One wave (64 threads) per block; 32 rows per wave.
// Lane l: h = l>>3 (owns one head -> exp computed with zero redundancy),
//         ng = l&7; rows = rg*32 + ng*4 + {0..3}  (4 rows/lane: each V
//         load amortizes over 4 output rows, halving V traffic vs 2 rows).
// j is split ATT_S ways across blocks; j unrolled x4 with float4 m loads.
// Partial (acc, wsum) written to ws.
// ---------------------------------------------------------------------------
__global__ __launch_bounds__(64) void attn_kernel(
    const float* __restrict__ m_dist,   // (B,N,N)
    const float* __restrict__ v,        // (B,N,128), c = h*16+d
    const float* __restrict__ rvec,     // 8 floats (head radii)
    const float* __restrict__ m102, const float* __restrict__ m103,
    float* __restrict__ part,           // (ATT_S, 4096, 128)
    float* __restrict__ wsum,           // (ATT_S, 4096, 8)
    int masked)
{
    const int blk = blockIdx.x;
    const int s  = blk & (ATT_S - 1);
    const int rg = blk >> 4;            // 0..127
    const int l  = threadIdx.x;
    const int h  = l >> 3, ng = l & 7;
    const int row0 = rg * 32 + ng * 4;  // rows row0..row0+3 (same batch: 32|2048)
    const int b  = row0 >> 11;

    const float r  = rvec[h];
    const float r2 = r * r;

    float thr[4] = {3.4028235e38f, 3.4028235e38f, 3.4028235e38f, 3.4028235e38f};
    if (masked) {
        // replicate tfp linear-percentile interpolation:
        // pos = 5/100*(N-1); frac = float32(pos - floor(pos))
        const double pos = 5.0 / 100.0 * 2047.0;
        const float FRAC = (float)(pos - 102.0);
        const float OM   = 1.0f - FRAC;
        #pragma unroll
        for (int i = 0; i < 4; ++i)
            thr[i] = (m102[row0 + i] * r2) * OM + (m103[row0 + i] * r2) * FRAC;
    }

    const float* mrow[4];
    #pragma unroll
    for (int i = 0; i < 4; ++i)
        mrow[i] = m_dist + ((size_t)b << 22) + ((size_t)((row0 + i) & 2047) << 11);
    const float* vb = v + ((size_t)b << 18) + (h << 4);

    float acc[4][16];
    #pragma unroll
    for (int i = 0; i < 4; ++i)
        #pragma unroll
        for (int d = 0; d < 16; ++d) acc[i][d] = 0.f;
    float wsm[4] = {0.f, 0.f, 0.f, 0.f};

    const int j0 = s * ATT_JS;
    for (int j = j0; j < j0 + ATT_JS; j += 4) {
        float4 mv[4];
        #pragma unroll
        for (int i = 0; i < 4; ++i) mv[i] = *(const float4*)(mrow[i] + j);

        float w[4][4];
        #pragma unroll
        for (int i = 0; i < 4; ++i) {
            float mm[4] = {mv[i].x, mv[i].y, mv[i].z, mv[i].w};
            #pragma unroll
            for (int jj = 0; jj < 4; ++jj) {
                float sd = mm[jj] * r2;
                float e  = (sd <= thr[i]) ? __expf(-sd) : 0.f;
                w[i][jj] = e;
                wsm[i] += e;
            }
        }

        #pragma unroll
        for (int jj = 0; jj < 4; ++jj) {
            const float4* vp = (const float4*)(vb + ((size_t)(j + jj) << 7));
            float va[16];
            *(float4*)(va)      = vp[0];
            *(float4*)(va + 4)  = vp[1];
            *(float4*)(va + 8)  = vp[2];
            *(float4*)(va + 12) = vp[3];
            #pragma unroll
            for (int i = 0; i < 4; ++i) {
                float wi = w[i][jj];
                #pragma unroll
                for (int d = 0; d < 16; ++d) acc[i][d] += wi * va[d];
            }
        }
    }

    #pragma unroll
    for (int i = 0; i < 4; ++i) {
        size_t po = (((size_t)s * 4096 + row0 + i) << 7) + (h << 4);
        float4* p = (float4*)(part + po);
        p[0] = make_float4(acc[i][0],  acc[i][1],  acc[i][2],  acc[i][3]);
        p[1] = make_float4(acc[i][4],  acc[i][5],  acc[i][6],  acc[i][7]);
        p[2] = make_float4(acc[i][8],  acc[i][9],  acc[i][10], acc[i][11]);
        p[3] = make_float4(acc[i][12], acc[i][13], acc[i][14], acc[i][15]);
        wsum[((size_t)s * 4096 + row0 + i) * 8 + h] = wsm[i];
    }
}

// Combine partials: out = gelu( sum_s acc / sum_s wsum )
__global__ __launch_bounds__(256) void attn_combine_kernel(
    const float* __restrict__ part, const float* __restrict__ wsum,
    float* __restrict__ out)
{
    int idx = blockIdx.x * 256 + threadIdx.x;   // 4096*128
    int row = idx >> 7, c = idx & 127, h = c >> 4;
    float a = 0.f, w = 0.f;
    #pragma unroll
    for (int s = 0; s < ATT_S; ++s) {
        a += part[((size_t)s * 4096 + row) * 128 + c];
        w += wsum[((size_t)s * 4096 + row) * 8 + h];
    }
    out[idx] = gelu_f(a / w);
}

// Final projection: out(4096,1) = t6(4096,128) @ W(128,1) + b
__global__ __launch_bounds__(256) void final_kernel(
    const float* __restrict__ X, const float* __restrict__ W,
    const float* __restrict__ b, float* __restrict__ out)
{
    int row = blockIdx.x * 256 + threadIdx.x;   // 4096
    const float4* x = (const float4*)(X + (size_t)row * 128);
    float acc = 0.f;
    #pragma unroll
    for (int k4 = 0; k4 < 32; ++k4) {
        float4 xv = x[k4];
        float4 wv = *(const float4*)(W + k4 * 4);
        acc += xv.x * wv.x + xv.y * wv.y + xv.z * wv.z + xv.w * wv.w;
    }
    out[row] = acc + b[0];
}

// ---------------------------------------------------------------------------
extern "C" void kernel_launch(void* const* d_in, const int* in_sizes, int n_in,
                              void* d_out, int out_size, void* d_ws, size_t ws_size,
                              hipStream_t stream)
{
    (void)in_sizes; (void)n_in; (void)out_size; (void)ws_size;
    const float* m_dist  = (const float*)d_in[0];
    const float* inputs  = (const float*)d_in[1];
    const float* en_W    = (const float*)d_in[2];
    const float* en_b    = (const float*)d_in[3];
    const float* down_r  = (const float*)d_in[4];
    const float* down_w  = (const float*)d_in[5];
    const float* mlp1_W1 = (const float*)d_in[6];
    const float* mlp1_b1 = (const float*)d_in[7];
    const float* mlp1_W2 = (const float*)d_in[8];
    const float* mlp1_b2 = (const float*)d_in[9];
    const float* w1_W    = (const float*)d_in[10];
    const float* w1_b    = (const float*)d_in[11];
    const float* pa_r    = (const float*)d_in[12];
    const float* pa_w    = (const float*)d_in[13];
    const float* blk_W1  = (const float*)d_in[14];
    const float* blk_b1  = (const float*)d_in[15];
    const float* blk_W2  = (const float*)d_in[16];
    const float* blk_b2  = (const float*)d_in[17];
    const float* wi_W    = (const float*)d_in[18];
    const float* wi_b    = (const float*)d_in[19];
    const float* up_r    = (const float*)d_in[20];
    const float* up_w    = (const float*)d_in[21];
    const float* mlp2_W1 = (const float*)d_in[22];
    const float* mlp2_b1 = (const float*)d_in[23];
    const float* mlp2_W2 = (const float*)d_in[24];
    const float* mlp2_b2 = (const float*)d_in[25];
    const float* w2_W    = (const float*)d_in[26];
    const float* w2_b    = (const float*)d_in[27];
    const float* de_W1   = (const float*)d_in[28];
    const float* de_b1   = (const float*)d_in[29];
    const float* de_W2   = (const float*)d_in[30];
    const float* de_b2   = (const float*)d_in[31];
    float* out = (float*)d_out;

    // workspace layout (floats); total ~50.4 MB
    const size_t BUF = (size_t)NROWS * HIDD;   // 524288
    float* w     = (float*)d_ws;
    float* ben   = w;
    float* bx0   = w + 1 * BUF;
    float* bx1   = w + 2 * BUF;
    float* bt    = w + 3 * BUF;
    float* bh    = w + 4 * BUF;
    float* br    = w + 5 * BUF;
    float* bv    = w + 6 * BUF;
    float* m102  = w + 7 * BUF;
    float* m103  = m102 + NROWS;
    float* part  = m103 + NROWS;                       // ATT_S*4096*128
    float* wsumb = part + (size_t)ATT_S * NROWS * HIDD; // ATT_S*4096*8

    dim3 b256(256), b64(64);
    dim3 gElem((NROWS * HIDD) / 256);   // 2048
    dim3 gMM(NROWS / 16);               // 256
    dim3 gAtt(128 * ATT_S);             // 2048 blocks (32 rows/wave)

    auto mm = [&](const float* X, const float* Wm, const float* bias,
                  const float* add, float* o, int vw, int g) {
        matmul128_kernel<<<gMM, b256, 0, stream>>>(X, Wm, bias, add, o, vw, g);
    };
    auto attn = [&](const float* x, const float* wv, const float* rv,
                    int masked, float* o) {
        mm(x, wv, nullptr, nullptr, bv, 1, 0);
        attn_kernel<<<gAtt, b64, 0, stream>>>(m_dist, bv, rv, m102, m103,
                                              part, wsumb, masked);
        attn_combine_kernel<<<gElem, b256, 0, stream>>>(part, wsumb, o);
    };

    // percentile thresholds (used by both masked mhpas)
    percentile_kernel<<<dim3(NROWS), b256, 0, stream>>>(m_dist, m102, m103);

    // encoder
    encoder_kernel<<<gElem, b256, 0, stream>>>(inputs, en_W, en_b, ben);

    // down block: x = gelu(mlp(mhpa(en, down, loc=5)) + en@w1_W + w1_b)
    attn(ben, down_w, down_r, 1, bh);
    mm(bh, mlp1_W1, mlp1_b1, nullptr, bt, 0, 1);
    mm(ben, w1_W, w1_b, nullptr, br, 0, 0);
    mm(bt, mlp1_W2, mlp1_b2, br, bx0, 0, 1);

    // 4 processor blocks (ping-pong x between bx0/bx1)
    float* xin = bx0;
    float* xout = bx1;
    for (int i = 0; i < 4; ++i) {
        attn(xin, pa_w + (size_t)i * NH * HIDD * VD, pa_r + (size_t)i * NH, 0, bh);
        mm(bh, blk_W1 + (size_t)i * HIDD * HIDD, blk_b1 + (size_t)i * HIDD,
           nullptr, bt, 0, 1);
        mm(xin, wi_W + (size_t)i * HIDD * HIDD, wi_b + (size_t)i * HIDD,
           nullptr, br, 0, 0);
        mm(bt, blk_W2 + (size_t)i * HIDD * HIDD, blk_b2 + (size_t)i * HIDD,
           br, xout, 0, 1);
        float* tmp = xin; xin = xout; xout = tmp;
    }
    // xin now holds x (== bx0 after 4 swaps)

    // up block: de = gelu(mlp(mhpa(x, up, loc=5)) + x@w2_W + w2_b)
    attn(xin, up_w, up_r, 1, bh);
    mm(bh, mlp2_W1, mlp2_b1, nullptr, bt, 0, 1);
    mm(xin, w2_W, w2_b, nullptr, br, 0, 0);
    mm(bt, mlp2_W2, mlp2_b2, br, xout, 0, 1);   // de -> xout (bx1)

    // decoder mlp
    mm(xout, de_W1, de_b1, nullptr, bt, 0, 1);
    final_kernel<<<dim3(NROWS / 256), b256, 0, stream>>>(bt, de_W2, de_b2, out);
}

// Round 3
// 1046.578 us; speedup vs baseline: 1.3343x; 1.0102x over previous
//
#include <hip/hip_runtime.h>
#include <cstddef>

// Problem constants
#define BSZ   2
#define NSEQ  2048
#define NROWS 4096        // B*N
#define HIDD  128
#define NH    8
#define VD    16
#define ATT_S 16          // j-splits for attention
#define ATT_JS (NSEQ/ATT_S)

__device__ __forceinline__ float gelu_f(float x) {
    // exact (erf) gelu, matching jax.nn.gelu(approximate=False) in fp32
    return 0.5f * x * (1.0f + erff(x * 0.70710678118654752440f));
}

// ---------------------------------------------------------------------------
// Per-row 5th-percentile support: emit the elements of sorted rank 102 and 103
// (0-indexed) of each m_dist row. Histogram select: 256 uniform bins over
// [0,1), wave-scan cumulative counts, collect the ~16 elements living in the
// rank-102/103 bins, exact rank by counting.
// ---------------------------------------------------------------------------
__global__ __launch_bounds__(256) void percentile_kernel(
    const float* __restrict__ m, float* __restrict__ m102, float* __restrict__ m103)
{
    __shared__ int   cnt[256];
    __shared__ int   cum[256];
    __shared__ float buf[192];
    __shared__ int   nc;
    __shared__ int   sb0, sb1, sbase;

    const int row = blockIdx.x;               // 0..4095 = b*2048+n
    const int t   = threadIdx.x;
    const float* mr = m + (size_t)row * 2048;

    float4 a = *(const float4*)(mr + t * 8);
    float4 c = *(const float4*)(mr + t * 8 + 4);
    float v[8] = {a.x, a.y, a.z, a.w, c.x, c.y, c.z, c.w};

    cnt[t] = 0;
    if (t == 0) nc = 0;
    __syncthreads();

    int bidx[8];
    #pragma unroll
    for (int i = 0; i < 8; ++i) {
        int bi = (int)(v[i] * 256.0f);
        bi = bi < 0 ? 0 : (bi > 255 ? 255 : bi);
        bidx[i] = bi;
        atomicAdd(&cnt[bi], 1);
    }
    __syncthreads();

    // inclusive prefix over 256 bins, done by wave 0 (4 bins/lane + shfl scan)
    if (t < 64) {
        int c0 = cnt[t * 4], c1 = cnt[t * 4 + 1], c2 = cnt[t * 4 + 2], c3 = cnt[t * 4 + 3];
        int s1 = c0 + c1, s2 = s1 + c2, s3 = s2 + c3;
        int sc = s3;
        #pragma unroll
        for (int off = 1; off < 64; off <<= 1) {
            int o = __shfl_up(sc, off);
            if (t >= off) sc += o;
        }
        int base = sc - s3;
        cum[t * 4]     = base + c0;
        cum[t * 4 + 1] = base + s1;
        cum[t * 4 + 2] = base + s2;
        cum[t * 4 + 3] = base + s3;
    }
    __syncthreads();

    {   // find the bins holding ranks 102 and 103 (exactly one thread each)
        int cprev = (t == 0) ? 0 : cum[t - 1];
        int cthis = cum[t];
        if (cprev < 103 && 103 <= cthis) { sb0 = t; sbase = cprev; }
        if (cprev < 104 && 104 <= cthis) { sb1 = t; }
    }
    __syncthreads();

    const int b0 = sb0, b1 = sb1, base = sbase;
    #pragma unroll
    for (int i = 0; i < 8; ++i) {
        if (bidx[i] >= b0 && bidx[i] <= b1) {
            int p = atomicAdd(&nc, 1);
            if (p < 192) buf[p] = v[i];
        }
    }
    __syncthreads();

    int n = nc; if (n > 192) n = 192;
    if (t < n) {
        float x = buf[t];
        int rk = base;
        for (int j = 0; j < n; ++j) {
            float y = buf[j];
            rk += (y < x || (y == x && j < t)) ? 1 : 0;
        }
        if (rk == 102) m102[row] = x;
        if (rk == 103) m103[row] = x;
    }
}

// ---------------------------------------------------------------------------
// Encoder: en = gelu(inputs(4096,3) @ W(3,128) + b)
// ---------------------------------------------------------------------------
__global__ __launch_bounds__(256) void encoder_kernel(
    const float* __restrict__ inp, const float* __restrict__ W,
    const float* __restrict__ b, float* __restrict__ out)
{
    int idx = blockIdx.x * 256 + threadIdx.x;   // 4096*128
    int row = idx >> 7, c = idx & 127;
    float x0 = inp[row * 3 + 0], x1 = inp[row * 3 + 1], x2 = inp[row * 3 + 2];
    float y = x0 * W[c] + x1 * W[128 + c] + x2 * W[256 + c] + b[c];
    out[idx] = gelu_f(y);
}

// ---------------------------------------------------------------------------
// Generic (4096,128) @ (128,128) matmul, W staged in LDS.
// vw_layout: W element (k,c) comes from w[(c>>4)*2048 + k*16 + (c&15)]
//            (reorders (H,HID,VD) head weights into a single (128,128) W).
// bias / addsrc nullable; optional gelu.
// ---------------------------------------------------------------------------
__global__ __launch_bounds__(256) void matmul128_kernel(
    const float* __restrict__ X, const float* __restrict__ W,
    const float* __restrict__ bias, const float* __restrict__ addsrc,
    float* __restrict__ out, int vw_layout, int do_gelu)
{
    __shared__ float Ws[128][128];   // 64 KB
    __shared__ float Xs[16][132];    // padded stride (132%4==0 keeps f4 align)
    const int t = threadIdx.x;
    const int row0 = blockIdx.x * 16;

    if (vw_layout) {
        for (int i = t; i < 16384; i += 256) {
            int k = i >> 7, c = i & 127;
            Ws[k][c] = W[((size_t)(c >> 4) << 11) + (k << 4) + (c & 15)];
        }
    } else {
        for (int i = t; i < 16384; i += 256) {
            Ws[i >> 7][i & 127] = W[i];
        }
    }
    for (int i = t; i < 16 * 32; i += 256) {
        int r = i >> 5, kk = (i & 31) << 2;
        float4 xv = *(const float4*)(X + (size_t)(row0 + r) * 128 + kk);
        *(float4*)&Xs[r][kk] = xv;
    }
    __syncthreads();

    const int cg = t & 31, rg = t >> 5;   // 32 col-groups x 8 row-groups
    const int c0 = cg << 2;
    const int r0 = rg << 1;               // 2 rows per thread -> 16 rows/block
    float acc[2][4] = {{0.f,0.f,0.f,0.f},{0.f,0.f,0.f,0.f}};

    for (int k = 0; k < 128; k += 4) {
        float4 xa = *(const float4*)&Xs[r0][k];
        float4 xb = *(const float4*)&Xs[r0 + 1][k];
        float xav[4] = {xa.x, xa.y, xa.z, xa.w};
        float xbv[4] = {xb.x, xb.y, xb.z, xb.w};
        #pragma unroll
        for (int kk = 0; kk < 4; ++kk) {
            float4 wv = *(const float4*)&Ws[k + kk][c0];
            acc[0][0] += xav[kk] * wv.x; acc[0][1] += xav[kk] * wv.y;
            acc[0][2] += xav[kk] * wv.z; acc[0][3] += xav[kk] * wv.w;
            acc[1][0] += xbv[kk] * wv.x; acc[1][1] += xbv[kk] * wv.y;
            acc[1][2] += xbv[kk] * wv.z; acc[1][3] += xbv[kk] * wv.w;
        }
    }

    #pragma unroll
    for (int i = 0; i < 2; ++i) {
        int r = row0 + r0 + i;
        float4 y;
        float* yp = (float*)&y;
        #pragma unroll
        for (int d = 0; d < 4; ++d) {
            float v = acc[i][d];
            if (bias)   v += bias[c0 + d];
            if (addsrc) v += addsrc[(size_t)r * 128 + c0 + d];
            if (do_gelu) v = gelu_f(v);
            yp[d] = v;
        }
        *(float4*)(out + (size_t)r * 128 + c0) = y;
    }
}

// ---------------------------------------------------------------------------
// Attention partial pass. One wave (64 threads) per block; 32 rows per wave.
// Lane l: h = l>>3 (owns one head -> exp computed with zero redundancy),
//         ng = l&7; rows = rg*32 + ng*4 + {0..3}  (4 rows/lane: each V
//         load amortizes over 4 output rows).
// j is split ATT_S ways across blocks; j unrolled x4 with float4 m loads.
// Partial (acc, wsum) written to ws.
//
// __launch_bounds__(64, 2): grid is 2048 waves = exactly 2 waves/EU, so a
// 2-waves/EU floor costs nothing and raises the VGPR cap to 256. Without it
// the compiler capped at 64 VGPRs and spilled the 64-float accumulator to
// scratch (measured: VGPR_Count=64, VALUBusy 23%, 116 us/dispatch).
// ---------------------------------------------------------------------------
__global__ __launch_bounds__(64, 2) void attn_kernel(
    const float* __restrict__ m_dist,   // (B,N,N)
    const float* __restrict__ v,        // (B,N,128), c = h*16+d
    const float* __restrict__ rvec,     // 8 floats (head radii)
    const float* __restrict__ m102, const float* __restrict__ m103,
    float* __restrict__ part,           // (ATT_S, 4096, 128)
    float* __restrict__ wsum,           // (ATT_S, 4096, 8)
    int masked)
{
    const int blk = blockIdx.x;
    const int s  = blk & (ATT_S - 1);
    const int rg = blk >> 4;            // 0..127
    const int l  = threadIdx.x;
    const int h  = l >> 3, ng = l & 7;
    const int row0 = rg * 32 + ng * 4;  // rows row0..row0+3 (same batch: 32|2048)
    const int b  = row0 >> 11;

    const float r  = rvec[h];
    const float r2 = r * r;

    float thr[4] = {3.4028235e38f, 3.4028235e38f, 3.4028235e38f, 3.4028235e38f};
    if (masked) {
        // replicate tfp linear-percentile interpolation:
        // pos = 5/100*(N-1); frac = float32(pos - floor(pos))
        const double pos = 5.0 / 100.0 * 2047.0;
        const float FRAC = (float)(pos - 102.0);
        const float OM   = 1.0f - FRAC;
        #pragma unroll
        for (int i = 0; i < 4; ++i)
            thr[i] = (m102[row0 + i] * r2) * OM + (m103[row0 + i] * r2) * FRAC;
    }

    const float* mrow[4];
    #pragma unroll
    for (int i = 0; i < 4; ++i)
        mrow[i] = m_dist + ((size_t)b << 22) + ((size_t)((row0 + i) & 2047) << 11);
    const float* vb = v + ((size_t)b << 18) + (h << 4);

    float acc[4][16];
    #pragma unroll
    for (int i = 0; i < 4; ++i)
        #pragma unroll
        for (int d = 0; d < 16; ++d) acc[i][d] = 0.f;
    float wsm[4] = {0.f, 0.f, 0.f, 0.f};

    const int j0 = s * ATT_JS;
    for (int j = j0; j < j0 + ATT_JS; j += 4) {
        float4 mv[4];
        #pragma unroll
        for (int i = 0; i < 4; ++i) mv[i] = *(const float4*)(mrow[i] + j);

        #pragma unroll
        for (int jj = 0; jj < 4; ++jj) {
            const float4* vp = (const float4*)(vb + ((size_t)(j + jj) << 7));
            float va[16];
            *(float4*)(va)      = vp[0];
            *(float4*)(va + 4)  = vp[1];
            *(float4*)(va + 8)  = vp[2];
            *(float4*)(va + 12) = vp[3];

            float w[4];
            #pragma unroll
            for (int i = 0; i < 4; ++i) {
                float mm = (jj == 0) ? mv[i].x : (jj == 1) ? mv[i].y
                         : (jj == 2) ? mv[i].z : mv[i].w;
                float sd = mm * r2;
                float e  = (sd <= thr[i]) ? __expf(-sd) : 0.f;
                w[i] = e;
                wsm[i] += e;
            }
            #pragma unroll
            for (int i = 0; i < 4; ++i) {
                float wi = w[i];
                #pragma unroll
                for (int d = 0; d < 16; ++d) acc[i][d] += wi * va[d];
            }
        }
    }

    #pragma unroll
    for (int i = 0; i < 4; ++i) {
        size_t po = (((size_t)s * 4096 + row0 + i) << 7) + (h << 4);
        float4* p = (float4*)(part + po);
        p[0] = make_float4(acc[i][0],  acc[i][1],  acc[i][2],  acc[i][3]);
        p[1] = make_float4(acc[i][4],  acc[i][5],  acc[i][6],  acc[i][7]);
        p[2] = make_float4(acc[i][8],  acc[i][9],  acc[i][10], acc[i][11]);
        p[3] = make_float4(acc[i][12], acc[i][13], acc[i][14], acc[i][15]);
        wsum[((size_t)s * 4096 + row0 + i) * 8 + h] = wsm[i];
    }
}

// Combine partials: out = gelu( sum_s acc / sum_s wsum )
__global__ __launch_bounds__(256) void attn_combine_kernel(
    const float* __restrict__ part, const float* __restrict__ wsum,
    float* __restrict__ out)
{
    int idx = blockIdx.x * 256 + threadIdx.x;   // 4096*128
    int row = idx >> 7, c = idx & 127, h = c >> 4;
    float a = 0.f, w = 0.f;
    #pragma unroll
    for (int s = 0; s < ATT_S; ++s) {
        a += part[((size_t)s * 4096 + row) * 128 + c];
        w += wsum[((size_t)s * 4096 + row) * 8 + h];
    }
    out[idx] = gelu_f(a / w);
}

// Final projection: out(4096,1) = t6(4096,128) @ W(128,1) + b
__global__ __launch_bounds__(256) void final_kernel(
    const float* __restrict__ X, const float* __restrict__ W,
    const float* __restrict__ b, float* __restrict__ out)
{
    int row = blockIdx.x * 256 + threadIdx.x;   // 4096
    const float4* x = (const float4*)(X + (size_t)row * 128);
    float acc = 0.f;
    #pragma unroll
    for (int k4 = 0; k4 < 32; ++k4) {
        float4 xv = x[k4];
        float4 wv = *(const float4*)(W + k4 * 4);
        acc += xv.x * wv.x + xv.y * wv.y + xv.z * wv.z + xv.w * wv.w;
    }
    out[row] = acc + b[0];
}

// ---------------------------------------------------------------------------
extern "C" void kernel_launch(void* const* d_in, const int* in_sizes, int n_in,
                              void* d_out, int out_size, void* d_ws, size_t ws_size,
                              hipStream_t stream)
{
    (void)in_sizes; (void)n_in; (void)out_size; (void)ws_size;
    const float* m_dist  = (const float*)d_in[0];
    const float* inputs  = (const float*)d_in[1];
    const float* en_W    = (const float*)d_in[2];
    const float* en_b    = (const float*)d_in[3];
    const float* down_r  = (const float*)d_in[4];
    const float* down_w  = (const float*)d_in[5];
    const float* mlp1_W1 = (const float*)d_in[6];
    const float* mlp1_b1 = (const float*)d_in[7];
    const float* mlp1_W2 = (const float*)d_in[8];
    const float* mlp1_b2 = (const float*)d_in[9];
    const float* w1_W    = (const float*)d_in[10];
    const float* w1_b    = (const float*)d_in[11];
    const float* pa_r    = (const float*)d_in[12];
    const float* pa_w    = (const float*)d_in[13];
    const float* blk_W1  = (const float*)d_in[14];
    const float* blk_b1  = (const float*)d_in[15];
    const float* blk_W2  = (const float*)d_in[16];
    const float* blk_b2  = (const float*)d_in[17];
    const float* wi_W    = (const float*)d_in[18];
    const float* wi_b    = (const float*)d_in[19];
    const float* up_r    = (const float*)d_in[20];
    const float* up_w    = (const float*)d_in[21];
    const float* mlp2_W1 = (const float*)d_in[22];
    const float* mlp2_b1 = (const float*)d_in[23];
    const float* mlp2_W2 = (const float*)d_in[24];
    const float* mlp2_b2 = (const float*)d_in[25];
    const float* w2_W    = (const float*)d_in[26];
    const float* w2_b    = (const float*)d_in[27];
    const float* de_W1   = (const float*)d_in[28];
    const float* de_b1   = (const float*)d_in[29];
    const float* de_W2   = (const float*)d_in[30];
    const float* de_b2   = (const float*)d_in[31];
    float* out = (float*)d_out;

    // workspace layout (floats); total ~50.4 MB
    const size_t BUF = (size_t)NROWS * HIDD;   // 524288
    float* w     = (float*)d_ws;
    float* ben   = w;
    float* bx0   = w + 1 * BUF;
    float* bx1   = w + 2 * BUF;
    float* bt    = w + 3 * BUF;
    float* bh    = w + 4 * BUF;
    float* br    = w + 5 * BUF;
    float* bv    = w + 6 * BUF;
    float* m102  = w + 7 * BUF;
    float* m103  = m102 + NROWS;
    float* part  = m103 + NROWS;                       // ATT_S*4096*128
    float* wsumb = part + (size_t)ATT_S * NROWS * HIDD; // ATT_S*4096*8

    dim3 b256(256), b64(64);
    dim3 gElem((NROWS * HIDD) / 256);   // 2048
    dim3 gMM(NROWS / 16);               // 256
    dim3 gAtt(128 * ATT_S);             // 2048 blocks (32 rows/wave)

    auto mm = [&](const float* X, const float* Wm, const float* bias,
                  const float* add, float* o, int vw, int g) {
        matmul128_kernel<<<gMM, b256, 0, stream>>>(X, Wm, bias, add, o, vw, g);
    };
    auto attn = [&](const float* x, const float* wv, const float* rv,
                    int masked, float* o) {
        mm(x, wv, nullptr, nullptr, bv, 1, 0);
        attn_kernel<<<gAtt, b64, 0, stream>>>(m_dist, bv, rv, m102, m103,
                                              part, wsumb, masked);
        attn_combine_kernel<<<gElem, b256, 0, stream>>>(part, wsumb, o);
    };

    // percentile thresholds (used by both masked mhpas)
    percentile_kernel<<<dim3(NROWS), b256, 0, stream>>>(m_dist, m102, m103);

    // encoder
    encoder_kernel<<<gElem, b256, 0, stream>>>(inputs, en_W, en_b, ben);

    // down block: x = gelu(mlp(mhpa(en, down, loc=5)) + en@w1_W + w1_b)
    attn(ben, down_w, down_r, 1, bh);
    mm(bh, mlp1_W1, mlp1_b1, nullptr, bt, 0, 1);
    mm(ben, w1_W, w1_b, nullptr, br, 0, 0);
    mm(bt, mlp1_W2, mlp1_b2, br, bx0, 0, 1);

    // 4 processor blocks (ping-pong x between bx0/bx1)
    float* xin = bx0;
    float* xout = bx1;
    for (int i = 0; i < 4; ++i) {
        attn(xin, pa_w + (size_t)i * NH * HIDD * VD, pa_r + (size_t)i * NH, 0, bh);
        mm(bh, blk_W1 + (size_t)i * HIDD * HIDD, blk_b1 + (size_t)i * HIDD,
           nullptr, bt, 0, 1);
        mm(xin, wi_W + (size_t)i * HIDD * HIDD, wi_b + (size_t)i * HIDD,
           nullptr, br, 0, 0);
        mm(bt, blk_W2 + (size_t)i * HIDD * HIDD, blk_b2 + (size_t)i * HIDD,
           br, xout, 0, 1);
        float* tmp = xin; xin = xout; xout = tmp;
    }
    // xin now holds x (== bx0 after 4 swaps)

    // up block: de = gelu(mlp(mhpa(x, up, loc=5)) + x@w2_W + w2_b)
    attn(xin, up_w, up_r, 1, bh);
    mm(bh, mlp2_W1, mlp2_b1, nullptr, bt, 0, 1);
    mm(xin, w2_W, w2_b, nullptr, br, 0, 0);
    mm(bt, mlp2_W2, mlp2_b2, br, xout, 0, 1);   // de -> xout (bx1)

    // decoder mlp
    mm(xout, de_W1, de_b1, nullptr, bt, 0, 1);
    final_kernel<<<dim3(NROWS / 256), b256, 0, stream>>>(bt, de_W2, de_b2, out);
}

// Round 4
// 1013.439 us; speedup vs baseline: 1.3780x; 1.0327x over previous
//
#include <hip/hip_runtime.h>
#include <cstddef>

// Problem constants
#define BSZ   2
#define NSEQ  2048
#define NROWS 4096        // B*N
#define HIDD  128
#define NH    8
#define VD    16
#define ATT_S 16          // j-splits for attention
#define ATT_JS (NSEQ/ATT_S)

__device__ __forceinline__ float gelu_f(float x) {
    // exact (erf) gelu, matching jax.nn.gelu(approximate=False) in fp32
    return 0.5f * x * (1.0f + erff(x * 0.70710678118654752440f));
}

// ---------------------------------------------------------------------------
// Per-row 5th-percentile support: emit the elements of sorted rank 102 and 103
// (0-indexed) of each m_dist row. Histogram select: 256 uniform bins over
// [0,1), wave-scan cumulative counts, collect the ~16 elements living in the
// rank-102/103 bins, exact rank by counting.
// ---------------------------------------------------------------------------
__global__ __launch_bounds__(256) void percentile_kernel(
    const float* __restrict__ m, float* __restrict__ m102, float* __restrict__ m103)
{
    __shared__ int   cnt[256];
    __shared__ int   cum[256];
    __shared__ float buf[192];
    __shared__ int   nc;
    __shared__ int   sb0, sb1, sbase;

    const int row = blockIdx.x;               // 0..4095 = b*2048+n
    const int t   = threadIdx.x;
    const float* mr = m + (size_t)row * 2048;

    float4 a = *(const float4*)(mr + t * 8);
    float4 c = *(const float4*)(mr + t * 8 + 4);
    float v[8] = {a.x, a.y, a.z, a.w, c.x, c.y, c.z, c.w};

    cnt[t] = 0;
    if (t == 0) nc = 0;
    __syncthreads();

    int bidx[8];
    #pragma unroll
    for (int i = 0; i < 8; ++i) {
        int bi = (int)(v[i] * 256.0f);
        bi = bi < 0 ? 0 : (bi > 255 ? 255 : bi);
        bidx[i] = bi;
        atomicAdd(&cnt[bi], 1);
    }
    __syncthreads();

    // inclusive prefix over 256 bins, done by wave 0 (4 bins/lane + shfl scan)
    if (t < 64) {
        int c0 = cnt[t * 4], c1 = cnt[t * 4 + 1], c2 = cnt[t * 4 + 2], c3 = cnt[t * 4 + 3];
        int s1 = c0 + c1, s2 = s1 + c2, s3 = s2 + c3;
        int sc = s3;
        #pragma unroll
        for (int off = 1; off < 64; off <<= 1) {
            int o = __shfl_up(sc, off);
            if (t >= off) sc += o;
        }
        int base = sc - s3;
        cum[t * 4]     = base + c0;
        cum[t * 4 + 1] = base + s1;
        cum[t * 4 + 2] = base + s2;
        cum[t * 4 + 3] = base + s3;
    }
    __syncthreads();

    {   // find the bins holding ranks 102 and 103 (exactly one thread each)
        int cprev = (t == 0) ? 0 : cum[t - 1];
        int cthis = cum[t];
        if (cprev < 103 && 103 <= cthis) { sb0 = t; sbase = cprev; }
        if (cprev < 104 && 104 <= cthis) { sb1 = t; }
    }
    __syncthreads();

    const int b0 = sb0, b1 = sb1, base = sbase;
    #pragma unroll
    for (int i = 0; i < 8; ++i) {
        if (bidx[i] >= b0 && bidx[i] <= b1) {
            int p = atomicAdd(&nc, 1);
            if (p < 192) buf[p] = v[i];
        }
    }
    __syncthreads();

    int n = nc; if (n > 192) n = 192;
    if (t < n) {
        float x = buf[t];
        int rk = base;
        for (int j = 0; j < n; ++j) {
            float y = buf[j];
            rk += (y < x || (y == x && j < t)) ? 1 : 0;
        }
        if (rk == 102) m102[row] = x;
        if (rk == 103) m103[row] = x;
    }
}

// ---------------------------------------------------------------------------
// Encoder: en = gelu(inputs(4096,3) @ W(3,128) + b)
// ---------------------------------------------------------------------------
__global__ __launch_bounds__(256) void encoder_kernel(
    const float* __restrict__ inp, const float* __restrict__ W,
    const float* __restrict__ b, float* __restrict__ out)
{
    int idx = blockIdx.x * 256 + threadIdx.x;   // 4096*128
    int row = idx >> 7, c = idx & 127;
    float x0 = inp[row * 3 + 0], x1 = inp[row * 3 + 1], x2 = inp[row * 3 + 2];
    float y = x0 * W[c] + x1 * W[128 + c] + x2 * W[256 + c] + b[c];
    out[idx] = gelu_f(y);
}

// ---------------------------------------------------------------------------
// Generic (4096,128) @ (128,128) matmul, W staged in LDS.
// vw_layout: W element (k,c) comes from w[(c>>4)*2048 + k*16 + (c&15)]
//            (reorders (H,HID,VD) head weights into a single (128,128) W).
// bias / addsrc nullable; optional gelu.
// ---------------------------------------------------------------------------
__global__ __launch_bounds__(256) void matmul128_kernel(
    const float* __restrict__ X, const float* __restrict__ W,
    const float* __restrict__ bias, const float* __restrict__ addsrc,
    float* __restrict__ out, int vw_layout, int do_gelu)
{
    __shared__ float Ws[128][128];   // 64 KB
    __shared__ float Xs[16][132];    // padded stride (132%4==0 keeps f4 align)
    const int t = threadIdx.x;
    const int row0 = blockIdx.x * 16;

    if (vw_layout) {
        for (int i = t; i < 16384; i += 256) {
            int k = i >> 7, c = i & 127;
            Ws[k][c] = W[((size_t)(c >> 4) << 11) + (k << 4) + (c & 15)];
        }
    } else {
        for (int i = t; i < 16384; i += 256) {
            Ws[i >> 7][i & 127] = W[i];
        }
    }
    for (int i = t; i < 16 * 32; i += 256) {
        int r = i >> 5, kk = (i & 31) << 2;
        float4 xv = *(const float4*)(X + (size_t)(row0 + r) * 128 + kk);
        *(float4*)&Xs[r][kk] = xv;
    }
    __syncthreads();

    const int cg = t & 31, rg = t >> 5;   // 32 col-groups x 8 row-groups
    const int c0 = cg << 2;
    const int r0 = rg << 1;               // 2 rows per thread -> 16 rows/block
    float acc[2][4] = {{0.f,0.f,0.f,0.f},{0.f,0.f,0.f,0.f}};

    for (int k = 0; k < 128; k += 4) {
        float4 xa = *(const float4*)&Xs[r0][k];
        float4 xb = *(const float4*)&Xs[r0 + 1][k];
        float xav[4] = {xa.x, xa.y, xa.z, xa.w};
        float xbv[4] = {xb.x, xb.y, xb.z, xb.w};
        #pragma unroll
        for (int kk = 0; kk < 4; ++kk) {
            float4 wv = *(const float4*)&Ws[k + kk][c0];
            acc[0][0] += xav[kk] * wv.x; acc[0][1] += xav[kk] * wv.y;
            acc[0][2] += xav[kk] * wv.z; acc[0][3] += xav[kk] * wv.w;
            acc[1][0] += xbv[kk] * wv.x; acc[1][1] += xbv[kk] * wv.y;
            acc[1][2] += xbv[kk] * wv.z; acc[1][3] += xbv[kk] * wv.w;
        }
    }

    #pragma unroll
    for (int i = 0; i < 2; ++i) {
        int r = row0 + r0 + i;
        float4 y;
        float* yp = (float*)&y;
        #pragma unroll
        for (int d = 0; d < 4; ++d) {
            float v = acc[i][d];
            if (bias)   v += bias[c0 + d];
            if (addsrc) v += addsrc[(size_t)r * 128 + c0 + d];
            if (do_gelu) v = gelu_f(v);
            yp[d] = v;
        }
        *(float4*)(out + (size_t)r * 128 + c0) = y;
    }
}

// ---------------------------------------------------------------------------
// Attention partial pass, d-SPLIT version. One wave (64 threads) per block;
// 32 rows per wave, but each block computes only 8 of the 16 V-dims (dh).
//
// Rationale (R3 post-mortem): the fused-16-dim version needed ~100 live VGPRs
// against the allocator's 64-VGPR cap -> AGPR round-trips on every FMA and no
// load pipelining (measured: VALUBusy 23%, 116us). launch_bounds hints did
// NOT move the allocation (R2->R3 identical counters), so instead we shrink
// the real demand: acc[4][8]=32 regs + va[8] + mv[16] ~ 85 live. Cost: m_dist
// read twice and exp computed twice (cheap); V traffic unchanged. Grid also
// doubles -> 4 waves/SIMD of TLP.
//
// Lane l: h = l>>3 (owns one head), ng = l&7; rows = rg*32 + ng*4 + {0..3}.
// Block: s = j-split (16), rg = row-group (128), dh = d-half (2).
// wsum written by dh==0 blocks only.
// ---------------------------------------------------------------------------
__global__ __launch_bounds__(64, 4) void attn_kernel(
    const float* __restrict__ m_dist,   // (B,N,N)
    const float* __restrict__ v,        // (B,N,128), c = h*16+d
    const float* __restrict__ rvec,     // 8 floats (head radii)
    const float* __restrict__ m102, const float* __restrict__ m103,
    float* __restrict__ part,           // (ATT_S, 4096, 128)
    float* __restrict__ wsum,           // (ATT_S, 4096, 8)
    int masked)
{
    const int blk = blockIdx.x;
    const int s  = blk & (ATT_S - 1);
    const int rg = (blk >> 4) & 127;    // 0..127
    const int dh = blk >> 11;           // 0..1 (d-half)
    const int l  = threadIdx.x;
    const int h  = l >> 3, ng = l & 7;
    const int row0 = rg * 32 + ng * 4;  // rows row0..row0+3 (same batch: 32|2048)
    const int b  = row0 >> 11;

    const float r  = rvec[h];
    const float r2 = r * r;

    float thr[4] = {3.4028235e38f, 3.4028235e38f, 3.4028235e38f, 3.4028235e38f};
    if (masked) {
        // replicate tfp linear-percentile interpolation:
        // pos = 5/100*(N-1); frac = float32(pos - floor(pos))
        const double pos = 5.0 / 100.0 * 2047.0;
        const float FRAC = (float)(pos - 102.0);
        const float OM   = 1.0f - FRAC;
        #pragma unroll
        for (int i = 0; i < 4; ++i)
            thr[i] = (m102[row0 + i] * r2) * OM + (m103[row0 + i] * r2) * FRAC;
    }

    const float* mrow[4];
    #pragma unroll
    for (int i = 0; i < 4; ++i)
        mrow[i] = m_dist + ((size_t)b << 22) + ((size_t)((row0 + i) & 2047) << 11);
    const float* vb = v + ((size_t)b << 18) + (h << 4) + (dh << 3);

    float acc[4][8];
    #pragma unroll
    for (int i = 0; i < 4; ++i)
        #pragma unroll
        for (int d = 0; d < 8; ++d) acc[i][d] = 0.f;
    float wsm[4] = {0.f, 0.f, 0.f, 0.f};

    const int j0 = s * ATT_JS;
    for (int j = j0; j < j0 + ATT_JS; j += 4) {
        float4 mv[4];
        #pragma unroll
        for (int i = 0; i < 4; ++i) mv[i] = *(const float4*)(mrow[i] + j);

        #pragma unroll
        for (int jj = 0; jj < 4; ++jj) {
            const float4* vp = (const float4*)(vb + ((size_t)(j + jj) << 7));
            float va[8];
            *(float4*)(va)     = vp[0];
            *(float4*)(va + 4) = vp[1];

            float w[4];
            #pragma unroll
            for (int i = 0; i < 4; ++i) {
                float mm = (jj == 0) ? mv[i].x : (jj == 1) ? mv[i].y
                         : (jj == 2) ? mv[i].z : mv[i].w;
                float sd = mm * r2;
                float e  = (sd <= thr[i]) ? __expf(-sd) : 0.f;
                w[i] = e;
                wsm[i] += e;
            }
            #pragma unroll
            for (int i = 0; i < 4; ++i) {
                float wi = w[i];
                #pragma unroll
                for (int d = 0; d < 8; ++d) acc[i][d] += wi * va[d];
            }
        }
    }

    #pragma unroll
    for (int i = 0; i < 4; ++i) {
        size_t po = (((size_t)s * 4096 + row0 + i) << 7) + (h << 4) + (dh << 3);
        float4* p = (float4*)(part + po);
        p[0] = make_float4(acc[i][0], acc[i][1], acc[i][2], acc[i][3]);
        p[1] = make_float4(acc[i][4], acc[i][5], acc[i][6], acc[i][7]);
        if (dh == 0)
            wsum[((size_t)s * 4096 + row0 + i) * 8 + h] = wsm[i];
    }
}

// Combine partials: out = gelu( sum_s acc / sum_s wsum )
__global__ __launch_bounds__(256) void attn_combine_kernel(
    const float* __restrict__ part, const float* __restrict__ wsum,
    float* __restrict__ out)
{
    int idx = blockIdx.x * 256 + threadIdx.x;   // 4096*128
    int row = idx >> 7, c = idx & 127, h = c >> 4;
    float a = 0.f, w = 0.f;
    #pragma unroll
    for (int s = 0; s < ATT_S; ++s) {
        a += part[((size_t)s * 4096 + row) * 128 + c];
        w += wsum[((size_t)s * 4096 + row) * 8 + h];
    }
    out[idx] = gelu_f(a / w);
}

// Final projection: out(4096,1) = t6(4096,128) @ W(128,1) + b
__global__ __launch_bounds__(256) void final_kernel(
    const float* __restrict__ X, const float* __restrict__ W,
    const float* __restrict__ b, float* __restrict__ out)
{
    int row = blockIdx.x * 256 + threadIdx.x;   // 4096
    const float4* x = (const float4*)(X + (size_t)row * 128);
    float acc = 0.f;
    #pragma unroll
    for (int k4 = 0; k4 < 32; ++k4) {
        float4 xv = x[k4];
        float4 wv = *(const float4*)(W + k4 * 4);
        acc += xv.x * wv.x + xv.y * wv.y + xv.z * wv.z + xv.w * wv.w;
    }
    out[row] = acc + b[0];
}

// ---------------------------------------------------------------------------
extern "C" void kernel_launch(void* const* d_in, const int* in_sizes, int n_in,
                              void* d_out, int out_size, void* d_ws, size_t ws_size,
                              hipStream_t stream)
{
    (void)in_sizes; (void)n_in; (void)out_size; (void)ws_size;
    const float* m_dist  = (const float*)d_in[0];
    const float* inputs  = (const float*)d_in[1];
    const float* en_W    = (const float*)d_in[2];
    const float* en_b    = (const float*)d_in[3];
    const float* down_r  = (const float*)d_in[4];
    const float* down_w  = (const float*)d_in[5];
    const float* mlp1_W1 = (const float*)d_in[6];
    const float* mlp1_b1 = (const float*)d_in[7];
    const float* mlp1_W2 = (const float*)d_in[8];
    const float* mlp1_b2 = (const float*)d_in[9];
    const float* w1_W    = (const float*)d_in[10];
    const float* w1_b    = (const float*)d_in[11];
    const float* pa_r    = (const float*)d_in[12];
    const float* pa_w    = (const float*)d_in[13];
    const float* blk_W1  = (const float*)d_in[14];
    const float* blk_b1  = (const float*)d_in[15];
    const float* blk_W2  = (const float*)d_in[16];
    const float* blk_b2  = (const float*)d_in[17];
    const float* wi_W    = (const float*)d_in[18];
    const float* wi_b    = (const float*)d_in[19];
    const float* up_r    = (const float*)d_in[20];
    const float* up_w    = (const float*)d_in[21];
    const float* mlp2_W1 = (const float*)d_in[22];
    const float* mlp2_b1 = (const float*)d_in[23];
    const float* mlp2_W2 = (const float*)d_in[24];
    const float* mlp2_b2 = (const float*)d_in[25];
    const float* w2_W    = (const float*)d_in[26];
    const float* w2_b    = (const float*)d_in[27];
    const float* de_W1   = (const float*)d_in[28];
    const float* de_b1   = (const float*)d_in[29];
    const float* de_W2   = (const float*)d_in[30];
    const float* de_b2   = (const float*)d_in[31];
    float* out = (float*)d_out;

    // workspace layout (floats); total ~50.4 MB
    const size_t BUF = (size_t)NROWS * HIDD;   // 524288
    float* w     = (float*)d_ws;
    float* ben   = w;
    float* bx0   = w + 1 * BUF;
    float* bx1   = w + 2 * BUF;
    float* bt    = w + 3 * BUF;
    float* bh    = w + 4 * BUF;
    float* br    = w + 5 * BUF;
    float* bv    = w + 6 * BUF;
    float* m102  = w + 7 * BUF;
    float* m103  = m102 + NROWS;
    float* part  = m103 + NROWS;                       // ATT_S*4096*128
    float* wsumb = part + (size_t)ATT_S * NROWS * HIDD; // ATT_S*4096*8

    dim3 b256(256), b64(64);
    dim3 gElem((NROWS * HIDD) / 256);   // 2048
    dim3 gMM(NROWS / 16);               // 256
    dim3 gAtt(128 * ATT_S * 2);         // 4096 blocks (32 rows/wave, d-split)

    auto mm = [&](const float* X, const float* Wm, const float* bias,
                  const float* add, float* o, int vw, int g) {
        matmul128_kernel<<<gMM, b256, 0, stream>>>(X, Wm, bias, add, o, vw, g);
    };
    auto attn = [&](const float* x, const float* wv, const float* rv,
                    int masked, float* o) {
        mm(x, wv, nullptr, nullptr, bv, 1, 0);
        attn_kernel<<<gAtt, b64, 0, stream>>>(m_dist, bv, rv, m102, m103,
                                              part, wsumb, masked);
        attn_combine_kernel<<<gElem, b256, 0, stream>>>(part, wsumb, o);
    };

    // percentile thresholds (used by both masked mhpas)
    percentile_kernel<<<dim3(NROWS), b256, 0, stream>>>(m_dist, m102, m103);

    // encoder
    encoder_kernel<<<gElem, b256, 0, stream>>>(inputs, en_W, en_b, ben);

    // down block: x = gelu(mlp(mhpa(en, down, loc=5)) + en@w1_W + w1_b)
    attn(ben, down_w, down_r, 1, bh);
    mm(bh, mlp1_W1, mlp1_b1, nullptr, bt, 0, 1);
    mm(ben, w1_W, w1_b, nullptr, br, 0, 0);
    mm(bt, mlp1_W2, mlp1_b2, br, bx0, 0, 1);

    // 4 processor blocks (ping-pong x between bx0/bx1)
    float* xin = bx0;
    float* xout = bx1;
    for (int i = 0; i < 4; ++i) {
        attn(xin, pa_w + (size_t)i * NH * HIDD * VD, pa_r + (size_t)i * NH, 0, bh);
        mm(bh, blk_W1 + (size_t)i * HIDD * HIDD, blk_b1 + (size_t)i * HIDD,
           nullptr, bt, 0, 1);
        mm(xin, wi_W + (size_t)i * HIDD * HIDD, wi_b + (size_t)i * HIDD,
           nullptr, br, 0, 0);
        mm(bt, blk_W2 + (size_t)i * HIDD * HIDD, blk_b2 + (size_t)i * HIDD,
           br, xout, 0, 1);
        float* tmp = xin; xin = xout; xout = tmp;
    }
    // xin now holds x (== bx0 after 4 swaps)

    // up block: de = gelu(mlp(mhpa(x, up, loc=5)) + x@w2_W + w2_b)
    attn(xin, up_w, up_r, 1, bh);
    mm(bh, mlp2_W1, mlp2_b1, nullptr, bt, 0, 1);
    mm(xin, w2_W, w2_b, nullptr, br, 0, 0);
    mm(bt, mlp2_W2, mlp2_b2, br, xout, 0, 1);   // de -> xout (bx1)

    // decoder mlp
    mm(xout, de_W1, de_b1, nullptr, bt, 0, 1);
    final_kernel<<<dim3(NROWS / 256), b256, 0, stream>>>(bt, de_W2, de_b2, out);
}

// Round 5
// 570.058 us; speedup vs baseline: 2.4497x; 1.7778x over previous
//
#include <hip/hip_runtime.h>
#include <cstddef>

// Problem constants
#define BSZ   2
#define NSEQ  2048
#define NROWS 4096        // B*N
#define HIDD  128
#define NH    8
#define VD    16

typedef __attribute__((ext_vector_type(8))) short bf16x8;
typedef __attribute__((ext_vector_type(4))) float f32x4;

__device__ __forceinline__ float gelu_f(float x) {
    // exact (erf) gelu, matching jax.nn.gelu(approximate=False) in fp32
    return 0.5f * x * (1.0f + erff(x * 0.70710678118654752440f));
}

__device__ __forceinline__ unsigned short bf16_rne(float f) {
    union { float f; unsigned u; } x; x.f = f;
    unsigned r = x.u + 0x7FFFu + ((x.u >> 16) & 1u);   // finite inputs only
    return (unsigned short)(r >> 16);
}

// ---------------------------------------------------------------------------
// Per-row 5th-percentile support: emit elements of sorted rank 102 and 103
// (0-indexed) of each m_dist row. Histogram select, 4 barriers.
// ---------------------------------------------------------------------------
__global__ __launch_bounds__(256) void percentile_kernel(
    const float* __restrict__ m, float* __restrict__ m102, float* __restrict__ m103)
{
    __shared__ int   cnt[256];
    __shared__ int   cum[256];
    __shared__ float buf[192];
    __shared__ int   nc;
    __shared__ int   sb0, sb1, sbase;

    const int row = blockIdx.x;               // 0..4095 = b*2048+n
    const int t   = threadIdx.x;
    const float* mr = m + (size_t)row * 2048;

    float4 a = *(const float4*)(mr + t * 8);
    float4 c = *(const float4*)(mr + t * 8 + 4);
    float v[8] = {a.x, a.y, a.z, a.w, c.x, c.y, c.z, c.w};

    cnt[t] = 0;
    if (t == 0) nc = 0;
    __syncthreads();

    int bidx[8];
    #pragma unroll
    for (int i = 0; i < 8; ++i) {
        int bi = (int)(v[i] * 256.0f);
        bi = bi < 0 ? 0 : (bi > 255 ? 255 : bi);
        bidx[i] = bi;
        atomicAdd(&cnt[bi], 1);
    }
    __syncthreads();

    if (t < 64) {
        int c0 = cnt[t * 4], c1 = cnt[t * 4 + 1], c2 = cnt[t * 4 + 2], c3 = cnt[t * 4 + 3];
        int s1 = c0 + c1, s2 = s1 + c2, s3 = s2 + c3;
        int sc = s3;
        #pragma unroll
        for (int off = 1; off < 64; off <<= 1) {
            int o = __shfl_up(sc, off);
            if (t >= off) sc += o;
        }
        int base = sc - s3;
        cum[t * 4]     = base + c0;
        cum[t * 4 + 1] = base + s1;
        cum[t * 4 + 2] = base + s2;
        cum[t * 4 + 3] = base + s3;
    }
    __syncthreads();

    {
        int cprev = (t == 0) ? 0 : cum[t - 1];
        int cthis = cum[t];
        if (cprev < 103 && 103 <= cthis) { sb0 = t; sbase = cprev; }
        if (cprev < 104 && 104 <= cthis) { sb1 = t; }
    }
    __syncthreads();

    const int b0 = sb0, b1 = sb1, base = sbase;
    #pragma unroll
    for (int i = 0; i < 8; ++i) {
        if (bidx[i] >= b0 && bidx[i] <= b1) {
            int p = atomicAdd(&nc, 1);
            if (p < 192) buf[p] = v[i];
        }
    }
    __syncthreads();

    int n = nc; if (n > 192) n = 192;
    if (t < n) {
        float x = buf[t];
        int rk = base;
        for (int j = 0; j < n; ++j) {
            float y = buf[j];
            rk += (y < x || (y == x && j < t)) ? 1 : 0;
        }
        if (rk == 102) m102[row] = x;
        if (rk == 103) m103[row] = x;
    }
}

// ---------------------------------------------------------------------------
// Encoder: en = gelu(inputs(4096,3) @ W(3,128) + b)
// ---------------------------------------------------------------------------
__global__ __launch_bounds__(256) void encoder_kernel(
    const float* __restrict__ inp, const float* __restrict__ W,
    const float* __restrict__ b, float* __restrict__ out)
{
    int idx = blockIdx.x * 256 + threadIdx.x;   // 4096*128
    int row = idx >> 7, c = idx & 127;
    float x0 = inp[row * 3 + 0], x1 = inp[row * 3 + 1], x2 = inp[row * 3 + 2];
    float y = x0 * W[c] + x1 * W[128 + c] + x2 * W[256 + c] + b[c];
    out[idx] = gelu_f(y);
}

// ---------------------------------------------------------------------------
// Generic (4096,128) @ (128,128) matmul, W staged in LDS.
// vw_layout: W element (k,c) comes from w[(c>>4)*2048 + k*16 + (c&15)].
// If vt != nullptr: instead of fp32 out, store bf16 V in MFMA-B blocked
// layout vblk[b][h][jt][q][d][jj]  (j = jt*32+q*8+jj, c = h*16+d) so the
// attention B-fragment load is one coalesced global_load_dwordx4 per lane.
// ---------------------------------------------------------------------------
__global__ __launch_bounds__(256) void matmul128_kernel(
    const float* __restrict__ X, const float* __restrict__ W,
    const float* __restrict__ bias, const float* __restrict__ addsrc,
    float* __restrict__ out, unsigned short* __restrict__ vt,
    int vw_layout, int do_gelu)
{
    __shared__ float Ws[128][128];   // 64 KB
    __shared__ float Xs[16][132];
    const int t = threadIdx.x;
    const int row0 = blockIdx.x * 16;

    if (vw_layout) {
        for (int i = t; i < 16384; i += 256) {
            int k = i >> 7, c = i & 127;
            Ws[k][c] = W[((size_t)(c >> 4) << 11) + (k << 4) + (c & 15)];
        }
    } else {
        for (int i = t; i < 16384; i += 256) {
            Ws[i >> 7][i & 127] = W[i];
        }
    }
    for (int i = t; i < 16 * 32; i += 256) {
        int r = i >> 5, kk = (i & 31) << 2;
        float4 xv = *(const float4*)(X + (size_t)(row0 + r) * 128 + kk);
        *(float4*)&Xs[r][kk] = xv;
    }
    __syncthreads();

    const int cg = t & 31, rg = t >> 5;
    const int c0 = cg << 2;
    const int r0 = rg << 1;
    float acc[2][4] = {{0.f,0.f,0.f,0.f},{0.f,0.f,0.f,0.f}};

    for (int k = 0; k < 128; k += 4) {
        float4 xa = *(const float4*)&Xs[r0][k];
        float4 xb = *(const float4*)&Xs[r0 + 1][k];
        float xav[4] = {xa.x, xa.y, xa.z, xa.w};
        float xbv[4] = {xb.x, xb.y, xb.z, xb.w};
        #pragma unroll
        for (int kk = 0; kk < 4; ++kk) {
            float4 wv = *(const float4*)&Ws[k + kk][c0];
            acc[0][0] += xav[kk] * wv.x; acc[0][1] += xav[kk] * wv.y;
            acc[0][2] += xav[kk] * wv.z; acc[0][3] += xav[kk] * wv.w;
            acc[1][0] += xbv[kk] * wv.x; acc[1][1] += xbv[kk] * wv.y;
            acc[1][2] += xbv[kk] * wv.z; acc[1][3] += xbv[kk] * wv.w;
        }
    }

    if (vt) {
        #pragma unroll
        for (int i = 0; i < 2; ++i) {
            int r = row0 + r0 + i;
            int bb = r >> 11, n = r & 2047;
            int jt = n >> 5, q = (n >> 3) & 3, jj = n & 7;
            #pragma unroll
            for (int d4 = 0; d4 < 4; ++d4) {
                int c = c0 + d4, h = c >> 4, dd = c & 15;
                size_t off = (((size_t)((bb * 8 + h) * 64 + jt) * 4 + q) << 7)
                           + (dd << 3) + jj;
                vt[off] = bf16_rne(acc[i][d4]);
            }
        }
        return;
    }

    #pragma unroll
    for (int i = 0; i < 2; ++i) {
        int r = row0 + r0 + i;
        float4 y;
        float* yp = (float*)&y;
        #pragma unroll
        for (int d = 0; d < 4; ++d) {
            float v = acc[i][d];
            if (bias)   v += bias[c0 + d];
            if (addsrc) v += addsrc[(size_t)r * 128 + c0 + d];
            if (do_gelu) v = gelu_f(v);
            yp[d] = v;
        }
        *(float4*)(out + (size_t)r * 128 + c0) = y;
    }
}

// ---------------------------------------------------------------------------
// Fused MFMA flash mhpa. Block = 16 rows, 512 threads = 8 waves
// (wave = jq*2+hg: jq = j-quarter of 2048, hg = head-group of 4).
// Per 32-j tile per lane: load 8 m_dist fp32 (A-layout rows: m = lane&15,
// k = quad*8+jj), compute masked exp once per head (reusing m across the 4
// heads), pack bf16 A-frag, and MFMA against a coalesced bf16 B-frag from
// the pre-blocked V. Row-sums in registers (quad butterfly); 4 j-quarter
// partials combined through LDS; epilogue = divide + gelu + store.
// Replaces scalar att@V (1.07G scalar FMA/mhpa -> MFMA) and eliminates the
// part/wsum global round-trip + combine kernel.
// ---------------------------------------------------------------------------
__global__ __launch_bounds__(512) void attn_mfma_kernel(
    const float* __restrict__ m_dist,        // (B,N,N) fp32
    const unsigned short* __restrict__ vblk, // bf16 blocked V
    const float* __restrict__ rvec,          // 8 head radii
    const float* __restrict__ m102, const float* __restrict__ m103,
    float* __restrict__ outp,                // (4096,128) gelu(att@V)
    int masked)
{
    __shared__ float partLDS[4][16][128];    // 32 KB
    __shared__ float sumLDS[4][8][16];       // 2 KB

    const int tid  = threadIdx.x;
    const int wave = tid >> 6, lane = tid & 63;
    const int hg = wave & 1, jq = wave >> 1;       // head-group, j-quarter
    const int q = lane >> 4, rn = lane & 15;       // quad, A-row-in-tile
    const int row0 = blockIdx.x * 16;
    const int row  = row0 + rn;
    const int b    = row0 >> 11;                   // 16 | 2048 -> same batch
    const int n    = row & 2047;

    // per-head constants (4 heads of this head-group)
    float r2[4], c2[4], thr[4];
    {
        const double pos = 5.0 / 100.0 * 2047.0;   // tfp percentile position
        const float FRAC = (float)(pos - 102.0);
        const float OM   = 1.0f - FRAC;
        float t102 = m102[row], t103 = m103[row];
        #pragma unroll
        for (int hh = 0; hh < 4; ++hh) {
            float r = rvec[hg * 4 + hh];
            r2[hh] = r * r;
            c2[hh] = -r2[hh] * 1.44269504088896340736f;  // -r^2*log2(e)
            thr[hh] = masked ? ((t102 * r2[hh]) * OM + (t103 * r2[hh]) * FRAC)
                             : 3.4028235e38f;
        }
    }

    const float* mrow = m_dist + ((size_t)b << 22) + ((size_t)n << 11);
    const unsigned short* vbase = vblk + (((size_t)(b * 8 + hg * 4)) << 15);
    // per head h: vbase + hh*(64*512) + jt*512 + lane*8

    f32x4 acc[4];
    #pragma unroll
    for (int hh = 0; hh < 4; ++hh) acc[hh] = (f32x4){0.f, 0.f, 0.f, 0.f};
    float rs[4] = {0.f, 0.f, 0.f, 0.f};

    for (int jt = jq * 16; jt < jq * 16 + 16; ++jt) {
        const int jb = (jt << 5) + (q << 3);
        float mv[8];
        *(float4*)(mv)     = *(const float4*)(mrow + jb);
        *(float4*)(mv + 4) = *(const float4*)(mrow + jb + 4);

        #pragma unroll
        for (int hh = 0; hh < 4; ++hh) {
            bf16x8 bfrag = *(const bf16x8*)(vbase + ((size_t)hh << 15)
                                            + ((size_t)jt << 9) + (lane << 3));
            float p[8];
            #pragma unroll
            for (int jj = 0; jj < 8; ++jj) {
                float sd = mv[jj] * r2[hh];
                float e  = exp2f(mv[jj] * c2[hh]);
                e = (sd <= thr[hh]) ? e : 0.f;
                rs[hh] += e;
                p[jj] = e;
            }
            bf16x8 afrag;
            #pragma unroll
            for (int jj = 0; jj < 8; ++jj) afrag[jj] = (short)bf16_rne(p[jj]);
            acc[hh] = __builtin_amdgcn_mfma_f32_16x16x32_bf16(afrag, bfrag,
                                                              acc[hh], 0, 0, 0);
        }
    }

    // full row-sum (row = rn) per head: butterfly across the 4 quads
    #pragma unroll
    for (int hh = 0; hh < 4; ++hh) {
        rs[hh] += __shfl_xor(rs[hh], 16);
        rs[hh] += __shfl_xor(rs[hh], 32);
    }
    if (lane < 16) {
        #pragma unroll
        for (int hh = 0; hh < 4; ++hh)
            sumLDS[jq][hg * 4 + hh][rn] = rs[hh];
    }
    // acc C-layout: D[row16 = q*4+reg][d = lane&15]
    #pragma unroll
    for (int hh = 0; hh < 4; ++hh) {
        #pragma unroll
        for (int reg = 0; reg < 4; ++reg)
            partLDS[jq][q * 4 + reg][(hg * 4 + hh) * 16 + rn] = acc[hh][reg];
    }
    __syncthreads();

    // epilogue: 2048 outputs, 4 contiguous per thread
    {
        int e0 = tid << 2;
        int ri = e0 >> 7, c0e = e0 & 127, h = c0e >> 4;
        float4 s = *(const float4*)&partLDS[0][ri][c0e];
        #pragma unroll
        for (int k = 1; k < 4; ++k) {
            float4 pz = *(const float4*)&partLDS[k][ri][c0e];
            s.x += pz.x; s.y += pz.y; s.z += pz.z; s.w += pz.w;
        }
        float l = sumLDS[0][h][ri] + sumLDS[1][h][ri]
                + sumLDS[2][h][ri] + sumLDS[3][h][ri];
        float inv = 1.0f / l;
        float4 o;
        o.x = gelu_f(s.x * inv); o.y = gelu_f(s.y * inv);
        o.z = gelu_f(s.z * inv); o.w = gelu_f(s.w * inv);
        *(float4*)(outp + (size_t)(row0 + ri) * 128 + c0e) = o;
    }
}

// Final projection: out(4096,1) = t6(4096,128) @ W(128,1) + b
__global__ __launch_bounds__(256) void final_kernel(
    const float* __restrict__ X, const float* __restrict__ W,
    const float* __restrict__ b, float* __restrict__ out)
{
    int row = blockIdx.x * 256 + threadIdx.x;   // 4096
    const float4* x = (const float4*)(X + (size_t)row * 128);
    float acc = 0.f;
    #pragma unroll
    for (int k4 = 0; k4 < 32; ++k4) {
        float4 xv = x[k4];
        float4 wv = *(const float4*)(W + k4 * 4);
        acc += xv.x * wv.x + xv.y * wv.y + xv.z * wv.z + xv.w * wv.w;
    }
    out[row] = acc + b[0];
}

// ---------------------------------------------------------------------------
extern "C" void kernel_launch(void* const* d_in, const int* in_sizes, int n_in,
                              void* d_out, int out_size, void* d_ws, size_t ws_size,
                              hipStream_t stream)
{
    (void)in_sizes; (void)n_in; (void)out_size; (void)ws_size;
    const float* m_dist  = (const float*)d_in[0];
    const float* inputs  = (const float*)d_in[1];
    const float* en_W    = (const float*)d_in[2];
    const float* en_b    = (const float*)d_in[3];
    const float* down_r  = (const float*)d_in[4];
    const float* down_w  = (const float*)d_in[5];
    const float* mlp1_W1 = (const float*)d_in[6];
    const float* mlp1_b1 = (const float*)d_in[7];
    const float* mlp1_W2 = (const float*)d_in[8];
    const float* mlp1_b2 = (const float*)d_in[9];
    const float* w1_W    = (const float*)d_in[10];
    const float* w1_b    = (const float*)d_in[11];
    const float* pa_r    = (const float*)d_in[12];
    const float* pa_w    = (const float*)d_in[13];
    const float* blk_W1  = (const float*)d_in[14];
    const float* blk_b1  = (const float*)d_in[15];
    const float* blk_W2  = (const float*)d_in[16];
    const float* blk_b2  = (const float*)d_in[17];
    const float* wi_W    = (const float*)d_in[18];
    const float* wi_b    = (const float*)d_in[19];
    const float* up_r    = (const float*)d_in[20];
    const float* up_w    = (const float*)d_in[21];
    const float* mlp2_W1 = (const float*)d_in[22];
    const float* mlp2_b1 = (const float*)d_in[23];
    const float* mlp2_W2 = (const float*)d_in[24];
    const float* mlp2_b2 = (const float*)d_in[25];
    const float* w2_W    = (const float*)d_in[26];
    const float* w2_b    = (const float*)d_in[27];
    const float* de_W1   = (const float*)d_in[28];
    const float* de_b1   = (const float*)d_in[29];
    const float* de_W2   = (const float*)d_in[30];
    const float* de_b2   = (const float*)d_in[31];
    float* out = (float*)d_out;

    // workspace layout (floats)
    const size_t BUF = (size_t)NROWS * HIDD;   // 524288
    float* w     = (float*)d_ws;
    float* ben   = w;
    float* bx0   = w + 1 * BUF;
    float* bx1   = w + 2 * BUF;
    float* bt    = w + 3 * BUF;
    float* bh    = w + 4 * BUF;
    float* br    = w + 5 * BUF;
    unsigned short* vblk = (unsigned short*)(w + 6 * BUF);  // 1 MB bf16 blocked V
    float* m102  = w + 7 * BUF;
    float* m103  = m102 + NROWS;

    dim3 b256(256), b512(512);
    dim3 gElem((NROWS * HIDD) / 256);   // 2048
    dim3 gMM(NROWS / 16);               // 256
    dim3 gAtt(NROWS / 16);              // 256 blocks x 512 thr

    auto mm = [&](const float* X, const float* Wm, const float* bias,
                  const float* add, float* o, int g) {
        matmul128_kernel<<<gMM, b256, 0, stream>>>(X, Wm, bias, add, o,
                                                   nullptr, 0, g);
    };
    auto attn = [&](const float* x, const float* wv, const float* rv,
                    int masked, float* o) {
        matmul128_kernel<<<gMM, b256, 0, stream>>>(x, wv, nullptr, nullptr,
                                                   nullptr, vblk, 1, 0);
        attn_mfma_kernel<<<gAtt, b512, 0, stream>>>(m_dist, vblk, rv,
                                                    m102, m103, o, masked);
    };

    // percentile thresholds (used by both masked mhpas)
    percentile_kernel<<<dim3(NROWS), b256, 0, stream>>>(m_dist, m102, m103);

    // encoder
    encoder_kernel<<<gElem, b256, 0, stream>>>(inputs, en_W, en_b, ben);

    // down block: x = gelu(mlp(mhpa(en, down, loc=5)) + en@w1_W + w1_b)
    attn(ben, down_w, down_r, 1, bh);
    mm(bh, mlp1_W1, mlp1_b1, nullptr, bt, 1);
    mm(ben, w1_W, w1_b, nullptr, br, 0);
    mm(bt, mlp1_W2, mlp1_b2, br, bx0, 1);

    // 4 processor blocks (ping-pong x between bx0/bx1)
    float* xin = bx0;
    float* xout = bx1;
    for (int i = 0; i < 4; ++i) {
        attn(xin, pa_w + (size_t)i * NH * HIDD * VD, pa_r + (size_t)i * NH, 0, bh);
        mm(bh, blk_W1 + (size_t)i * HIDD * HIDD, blk_b1 + (size_t)i * HIDD,
           nullptr, bt, 1);
        mm(xin, wi_W + (size_t)i * HIDD * HIDD, wi_b + (size_t)i * HIDD,
           nullptr, br, 0);
        mm(bt, blk_W2 + (size_t)i * HIDD * HIDD, blk_b2 + (size_t)i * HIDD,
           br, xout, 1);
        float* tmp = xin; xin = xout; xout = tmp;
    }
    // xin now holds x (== bx0 after 4 swaps)

    // up block: de = gelu(mlp(mhpa(x, up, loc=5)) + x@w2_W + w2_b)
    attn(xin, up_w, up_r, 1, bh);
    mm(bh, mlp2_W1, mlp2_b1, nullptr, bt, 1);
    mm(xin, w2_W, w2_b, nullptr, br, 0);
    mm(bt, mlp2_W2, mlp2_b2, br, xout, 1);   // de -> xout (bx1)

    // decoder mlp
    mm(xout, de_W1, de_b1, nullptr, bt, 1);
    final_kernel<<<dim3(NROWS / 256), b256, 0, stream>>>(bt, de_W2, de_b2, out);
}

// Round 6
// 458.152 us; speedup vs baseline: 3.0481x; 1.2443x over previous
//
#include <hip/hip_runtime.h>
#include <cstddef>

// Problem constants
#define BSZ   2
#define NSEQ  2048
#define NROWS 4096        // B*N
#define HIDD  128
#define NH    8
#define VD    16

typedef __attribute__((ext_vector_type(8))) short bf16x8;
typedef __attribute__((ext_vector_type(4))) float f32x4;

__device__ __forceinline__ float gelu_f(float x) {
    // exact (erf) gelu, matching jax.nn.gelu(approximate=False) in fp32
    return 0.5f * x * (1.0f + erff(x * 0.70710678118654752440f));
}

__device__ __forceinline__ unsigned short bf16_rne(float f) {
    union { float f; unsigned u; } x; x.f = f;
    unsigned r = x.u + 0x7FFFu + ((x.u >> 16) & 1u);   // finite inputs only
    return (unsigned short)(r >> 16);
}
__device__ __forceinline__ float bf16_to_f(unsigned short h) {
    union { unsigned u; float f; } x; x.u = ((unsigned)h) << 16;
    return x.f;
}

// ---------------------------------------------------------------------------
// Per-row 5th-percentile support: ranks 102/103 of each m_dist row.
// Histogram select, 4 barriers.
// ---------------------------------------------------------------------------
__global__ __launch_bounds__(256) void percentile_kernel(
    const float* __restrict__ m, float* __restrict__ m102, float* __restrict__ m103)
{
    __shared__ int   cnt[256];
    __shared__ int   cum[256];
    __shared__ float buf[192];
    __shared__ int   nc;
    __shared__ int   sb0, sb1, sbase;

    const int row = blockIdx.x;               // 0..4095 = b*2048+n
    const int t   = threadIdx.x;
    const float* mr = m + (size_t)row * 2048;

    float4 a = *(const float4*)(mr + t * 8);
    float4 c = *(const float4*)(mr + t * 8 + 4);
    float v[8] = {a.x, a.y, a.z, a.w, c.x, c.y, c.z, c.w};

    cnt[t] = 0;
    if (t == 0) nc = 0;
    __syncthreads();

    int bidx[8];
    #pragma unroll
    for (int i = 0; i < 8; ++i) {
        int bi = (int)(v[i] * 256.0f);
        bi = bi < 0 ? 0 : (bi > 255 ? 255 : bi);
        bidx[i] = bi;
        atomicAdd(&cnt[bi], 1);
    }
    __syncthreads();

    if (t < 64) {
        int c0 = cnt[t * 4], c1 = cnt[t * 4 + 1], c2 = cnt[t * 4 + 2], c3 = cnt[t * 4 + 3];
        int s1 = c0 + c1, s2 = s1 + c2, s3 = s2 + c3;
        int sc = s3;
        #pragma unroll
        for (int off = 1; off < 64; off <<= 1) {
            int o = __shfl_up(sc, off);
            if (t >= off) sc += o;
        }
        int base = sc - s3;
        cum[t * 4]     = base + c0;
        cum[t * 4 + 1] = base + s1;
        cum[t * 4 + 2] = base + s2;
        cum[t * 4 + 3] = base + s3;
    }
    __syncthreads();

    {
        int cprev = (t == 0) ? 0 : cum[t - 1];
        int cthis = cum[t];
        if (cprev < 103 && 103 <= cthis) { sb0 = t; sbase = cprev; }
        if (cprev < 104 && 104 <= cthis) { sb1 = t; }
    }
    __syncthreads();

    const int b0 = sb0, b1 = sb1, base = sbase;
    #pragma unroll
    for (int i = 0; i < 8; ++i) {
        if (bidx[i] >= b0 && bidx[i] <= b1) {
            int p = atomicAdd(&nc, 1);
            if (p < 192) buf[p] = v[i];
        }
    }
    __syncthreads();

    int n = nc; if (n > 192) n = 192;
    if (t < n) {
        float x = buf[t];
        int rk = base;
        for (int j = 0; j < n; ++j) {
            float y = buf[j];
            rk += (y < x || (y == x && j < t)) ? 1 : 0;
        }
        if (rk == 102) m102[row] = x;
        if (rk == 103) m103[row] = x;
    }
}

// ---------------------------------------------------------------------------
// Encoder: en = gelu(inputs(4096,3) @ W(3,128) + b)
// ---------------------------------------------------------------------------
__global__ __launch_bounds__(256) void encoder_kernel(
    const float* __restrict__ inp, const float* __restrict__ W,
    const float* __restrict__ b, float* __restrict__ out)
{
    int idx = blockIdx.x * 256 + threadIdx.x;   // 4096*128
    int row = idx >> 7, c = idx & 127;
    float x0 = inp[row * 3 + 0], x1 = inp[row * 3 + 1], x2 = inp[row * 3 + 2];
    float y = x0 * W[c] + x1 * W[128 + c] + x2 * W[256 + c] + b[c];
    out[idx] = gelu_f(y);
}

// ---------------------------------------------------------------------------
// Weight prep: convert each 128x128 fp32 weight into MFMA-B blocked bf16
// hi/lo planes (split-bf16: W = hi + lo, rel err ~2^-17).
// Dest layout per matrix (16384 ushort per plane, lo plane at +16384):
//   off = (nt*4+kt)*512 + q*128 + n16*8 + jj
//   element = W[k = kt*32+q*8+jj][c = nt*16+n16]
// so a lane (q*16+n16) reads its B-fragment as one 16B load at off=...+lane*8.
// vw weights ((H,HID,VD) head projections): element (k,c) at
// src[nt*2048 + k*16 + n16].
// ---------------------------------------------------------------------------
struct PrepArgs { const float* src[25]; unsigned vwmask; };

__global__ __launch_bounds__(256) void prep_kernel(PrepArgs a,
                                                   unsigned short* __restrict__ dst)
{
    const int mat = blockIdx.x >> 2, chunk = blockIdx.x & 3;
    const float* __restrict__ W = a.src[mat];
    const int vw = (a.vwmask >> mat) & 1;
    unsigned short* __restrict__ base = dst + (size_t)mat * 32768;
    for (int o = chunk * 4096 + threadIdx.x; o < chunk * 4096 + 4096; o += 256) {
        int nt = o >> 11, kt = (o >> 9) & 3, q = (o >> 7) & 3;
        int n16 = (o >> 3) & 15, jj = o & 7;
        int k = kt * 32 + q * 8 + jj;
        float w = vw ? W[nt * 2048 + k * 16 + n16]
                     : W[k * 128 + nt * 16 + n16];
        unsigned short h = bf16_rne(w);
        unsigned short l = bf16_rne(w - bf16_to_f(h));
        base[o] = h;
        base[16384 + o] = l;
    }
}

// ---------------------------------------------------------------------------
// Split-bf16 MFMA matmul body: out(16 rows) = X(16x128) @ W(128x128).
// No LDS, no W staging: B hi/lo fragments are coalesced 16B/lane loads from
// the pre-blocked weights (L2-hot); A tile loaded from global in the verified
// A-layout (A[m=lane&15][k=quad*8+jj]) and hi/lo-split in registers.
// X@W = Ahi@Bhi + Ahi@Blo + Alo@Bhi  (lo@lo dropped, ~2^-18 rel).
// Epilogue: +bias, +addsrc, optional gelu; or bf16 store into the blocked
// V layout (vt) consumed by attn_mfma_kernel.
// ---------------------------------------------------------------------------
__device__ __forceinline__ void mfma_mm_body(
    int blk, const float* __restrict__ X, const unsigned short* __restrict__ Bw,
    const float* __restrict__ bias, const float* __restrict__ addsrc,
    float* __restrict__ out, unsigned short* __restrict__ vt, int do_gelu)
{
    const int tid = threadIdx.x;
    const int wave = tid >> 6, lane = tid & 63;
    const int q = lane >> 4, mr = lane & 15;
    const int row0 = blk * 16;

    // A tile: 4 k-tiles x 8 elems, hi/lo split
    bf16x8 ahi[4], alo[4];
    const float* xr = X + (size_t)(row0 + mr) * 128 + q * 8;
    #pragma unroll
    for (int kt = 0; kt < 4; ++kt) {
        float av[8];
        *(float4*)(av)     = *(const float4*)(xr + kt * 32);
        *(float4*)(av + 4) = *(const float4*)(xr + kt * 32 + 4);
        #pragma unroll
        for (int j = 0; j < 8; ++j) {
            unsigned short h = bf16_rne(av[j]);
            unsigned short l = bf16_rne(av[j] - bf16_to_f(h));
            ahi[kt][j] = (short)h;
            alo[kt][j] = (short)l;
        }
    }

    #pragma unroll
    for (int ct = 0; ct < 2; ++ct) {
        const int nt = wave * 2 + ct;              // col-tile 0..7
        const unsigned short* bp = Bw + (size_t)nt * 2048 + lane * 8;
        f32x4 acc = (f32x4){0.f, 0.f, 0.f, 0.f};
        #pragma unroll
        for (int kt = 0; kt < 4; ++kt) {
            bf16x8 bhi = *(const bf16x8*)(bp + kt * 512);
            bf16x8 blo = *(const bf16x8*)(bp + 16384 + kt * 512);
            acc = __builtin_amdgcn_mfma_f32_16x16x32_bf16(ahi[kt], bhi, acc, 0, 0, 0);
            acc = __builtin_amdgcn_mfma_f32_16x16x32_bf16(ahi[kt], blo, acc, 0, 0, 0);
            acc = __builtin_amdgcn_mfma_f32_16x16x32_bf16(alo[kt], bhi, acc, 0, 0, 0);
        }

        const int c = nt * 16 + mr;                // output column
        const float bv = bias ? bias[c] : 0.f;
        #pragma unroll
        for (int reg = 0; reg < 4; ++reg) {
            const int r = row0 + q * 4 + reg;      // D: row=q*4+reg, col=lane&15
            float v2 = acc[reg] + bv;
            if (addsrc) v2 += addsrc[(size_t)r * 128 + c];
            if (do_gelu) v2 = gelu_f(v2);
            if (vt) {
                int bb = r >> 11, n = r & 2047;
                int jt = n >> 5, q2 = (n >> 3) & 3, jj = n & 7;
                int h = c >> 4, dd = c & 15;
                size_t off = (((size_t)(bb * 8 + h) * 64 + jt) * 4 + q2) * 128
                           + (dd << 3) + jj;
                vt[off] = bf16_rne(v2);
            } else {
                out[(size_t)r * 128 + c] = v2;
            }
        }
    }
}

__global__ __launch_bounds__(256) void mfma_mm_kernel(
    const float* __restrict__ X, const unsigned short* __restrict__ Bw,
    const float* __restrict__ bias, const float* __restrict__ addsrc,
    float* __restrict__ out, unsigned short* __restrict__ vt, int do_gelu)
{
    mfma_mm_body(blockIdx.x, X, Bw, bias, addsrc, out, vt, do_gelu);
}

// two independent matmuls in one launch (grid 512) — halves the dependent
// launch chain in each MLP section and fills the chip better.
__global__ __launch_bounds__(256) void mfma_mm_dual_kernel(
    const float* __restrict__ X0, const unsigned short* __restrict__ B0,
    const float* __restrict__ bias0, float* __restrict__ out0, int g0,
    const float* __restrict__ X1, const unsigned short* __restrict__ B1,
    const float* __restrict__ bias1, float* __restrict__ out1, int g1)
{
    if (blockIdx.x < 256)
        mfma_mm_body(blockIdx.x, X0, B0, bias0, nullptr, out0, nullptr, g0);
    else
        mfma_mm_body(blockIdx.x - 256, X1, B1, bias1, nullptr, out1, nullptr, g1);
}

// ---------------------------------------------------------------------------
// Fused MFMA flash mhpa (validated R5). Block = 16 rows, 512 thr = 8 waves
// (wave = jq*2+hg). Per 32-j tile per lane: 8 m_dist fp32 loads reused across
// 4 heads; masked exp -> bf16 A-frag; MFMA vs coalesced bf16 B-frag from the
// pre-blocked V. Row-sums via quad butterfly; partials combined in LDS.
// ---------------------------------------------------------------------------
__global__ __launch_bounds__(512) void attn_mfma_kernel(
    const float* __restrict__ m_dist,        // (B,N,N) fp32
    const unsigned short* __restrict__ vblk, // bf16 blocked V
    const float* __restrict__ rvec,          // 8 head radii
    const float* __restrict__ m102, const float* __restrict__ m103,
    float* __restrict__ outp,                // (4096,128) gelu(att@V)
    int masked)
{
    __shared__ float partLDS[4][16][128];    // 32 KB
    __shared__ float sumLDS[4][8][16];       // 2 KB

    const int tid  = threadIdx.x;
    const int wave = tid >> 6, lane = tid & 63;
    const int hg = wave & 1, jq = wave >> 1;       // head-group, j-quarter
    const int q = lane >> 4, rn = lane & 15;       // quad, A-row-in-tile
    const int row0 = blockIdx.x * 16;
    const int row  = row0 + rn;
    const int b    = row0 >> 11;                   // 16 | 2048 -> same batch
    const int n    = row & 2047;

    float r2[4], c2[4], thr[4];
    {
        const double pos = 5.0 / 100.0 * 2047.0;   // tfp percentile position
        const float FRAC = (float)(pos - 102.0);
        const float OM   = 1.0f - FRAC;
        float t102 = m102[row], t103 = m103[row];
        #pragma unroll
        for (int hh = 0; hh < 4; ++hh) {
            float r = rvec[hg * 4 + hh];
            r2[hh] = r * r;
            c2[hh] = -r2[hh] * 1.44269504088896340736f;  // -r^2*log2(e)
            thr[hh] = masked ? ((t102 * r2[hh]) * OM + (t103 * r2[hh]) * FRAC)
                             : 3.4028235e38f;
        }
    }

    const float* mrow = m_dist + ((size_t)b << 22) + ((size_t)n << 11);
    const unsigned short* vbase = vblk + (((size_t)(b * 8 + hg * 4)) << 15);

    f32x4 acc[4];
    #pragma unroll
    for (int hh = 0; hh < 4; ++hh) acc[hh] = (f32x4){0.f, 0.f, 0.f, 0.f};
    float rs[4] = {0.f, 0.f, 0.f, 0.f};

    for (int jt = jq * 16; jt < jq * 16 + 16; ++jt) {
        const int jb = (jt << 5) + (q << 3);
        float mv[8];
        *(float4*)(mv)     = *(const float4*)(mrow + jb);
        *(float4*)(mv + 4) = *(const float4*)(mrow + jb + 4);

        #pragma unroll
        for (int hh = 0; hh < 4; ++hh) {
            bf16x8 bfrag = *(const bf16x8*)(vbase + ((size_t)hh << 15)
                                            + ((size_t)jt << 9) + (lane << 3));
            float p[8];
            #pragma unroll
            for (int jj = 0; jj < 8; ++jj) {
                float sd = mv[jj] * r2[hh];
                float e  = exp2f(mv[jj] * c2[hh]);
                e = (sd <= thr[hh]) ? e : 0.f;
                rs[hh] += e;
                p[jj] = e;
            }
            bf16x8 afrag;
            #pragma unroll
            for (int jj = 0; jj < 8; ++jj) afrag[jj] = (short)bf16_rne(p[jj]);
            acc[hh] = __builtin_amdgcn_mfma_f32_16x16x32_bf16(afrag, bfrag,
                                                              acc[hh], 0, 0, 0);
        }
    }

    #pragma unroll
    for (int hh = 0; hh < 4; ++hh) {
        rs[hh] += __shfl_xor(rs[hh], 16);
        rs[hh] += __shfl_xor(rs[hh], 32);
    }
    if (lane < 16) {
        #pragma unroll
        for (int hh = 0; hh < 4; ++hh)
            sumLDS[jq][hg * 4 + hh][rn] = rs[hh];
    }
    #pragma unroll
    for (int hh = 0; hh < 4; ++hh) {
        #pragma unroll
        for (int reg = 0; reg < 4; ++reg)
            partLDS[jq][q * 4 + reg][(hg * 4 + hh) * 16 + rn] = acc[hh][reg];
    }
    __syncthreads();

    {
        int e0 = tid << 2;
        int ri = e0 >> 7, c0e = e0 & 127, h = c0e >> 4;
        float4 s = *(const float4*)&partLDS[0][ri][c0e];
        #pragma unroll
        for (int k = 1; k < 4; ++k) {
            float4 pz = *(const float4*)&partLDS[k][ri][c0e];
            s.x += pz.x; s.y += pz.y; s.z += pz.z; s.w += pz.w;
        }
        float l = sumLDS[0][h][ri] + sumLDS[1][h][ri]
                + sumLDS[2][h][ri] + sumLDS[3][h][ri];
        float inv = 1.0f / l;
        float4 o;
        o.x = gelu_f(s.x * inv); o.y = gelu_f(s.y * inv);
        o.z = gelu_f(s.z * inv); o.w = gelu_f(s.w * inv);
        *(float4*)(outp + (size_t)(row0 + ri) * 128 + c0e) = o;
    }
}

// Final projection: out(4096,1) = t6(4096,128) @ W(128,1) + b
__global__ __launch_bounds__(256) void final_kernel(
    const float* __restrict__ X, const float* __restrict__ W,
    const float* __restrict__ b, float* __restrict__ out)
{
    int row = blockIdx.x * 256 + threadIdx.x;   // 4096
    const float4* x = (const float4*)(X + (size_t)row * 128);
    float acc = 0.f;
    #pragma unroll
    for (int k4 = 0; k4 < 32; ++k4) {
        float4 xv = x[k4];
        float4 wv = *(const float4*)(W + k4 * 4);
        acc += xv.x * wv.x + xv.y * wv.y + xv.z * wv.z + xv.w * wv.w;
    }
    out[row] = acc + b[0];
}

// ---------------------------------------------------------------------------
extern "C" void kernel_launch(void* const* d_in, const int* in_sizes, int n_in,
                              void* d_out, int out_size, void* d_ws, size_t ws_size,
                              hipStream_t stream)
{
    (void)in_sizes; (void)n_in; (void)out_size; (void)ws_size;
    const float* m_dist  = (const float*)d_in[0];
    const float* inputs  = (const float*)d_in[1];
    const float* en_W    = (const float*)d_in[2];
    const float* en_b    = (const float*)d_in[3];
    const float* down_r  = (const float*)d_in[4];
    const float* down_w  = (const float*)d_in[5];
    const float* mlp1_W1 = (const float*)d_in[6];
    const float* mlp1_b1 = (const float*)d_in[7];
    const float* mlp1_W2 = (const float*)d_in[8];
    const float* mlp1_b2 = (const float*)d_in[9];
    const float* w1_W    = (const float*)d_in[10];
    const float* w1_b    = (const float*)d_in[11];
    const float* pa_r    = (const float*)d_in[12];
    const float* pa_w    = (const float*)d_in[13];
    const float* blk_W1  = (const float*)d_in[14];
    const float* blk_b1  = (const float*)d_in[15];
    const float* blk_W2  = (const float*)d_in[16];
    const float* blk_b2  = (const float*)d_in[17];
    const float* wi_W    = (const float*)d_in[18];
    const float* wi_b    = (const float*)d_in[19];
    const float* up_r    = (const float*)d_in[20];
    const float* up_w    = (const float*)d_in[21];
    const float* mlp2_W1 = (const float*)d_in[22];
    const float* mlp2_b1 = (const float*)d_in[23];
    const float* mlp2_W2 = (const float*)d_in[24];
    const float* mlp2_b2 = (const float*)d_in[25];
    const float* w2_W    = (const float*)d_in[26];
    const float* w2_b    = (const float*)d_in[27];
    const float* de_W1   = (const float*)d_in[28];
    const float* de_b1   = (const float*)d_in[29];
    const float* de_W2   = (const float*)d_in[30];
    const float* de_b2   = (const float*)d_in[31];
    float* out = (float*)d_out;

    // workspace layout (floats)
    const size_t BUF = (size_t)NROWS * HIDD;   // 524288
    float* w     = (float*)d_ws;
    float* ben   = w;
    float* bx0   = w + 1 * BUF;
    float* bx1   = w + 2 * BUF;
    float* bt    = w + 3 * BUF;
    float* bh    = w + 4 * BUF;
    float* br    = w + 5 * BUF;
    unsigned short* vblk = (unsigned short*)(w + 6 * BUF);  // 1 MB bf16 blocked V
    float* m102  = w + 7 * BUF;
    float* m103  = m102 + NROWS;
    unsigned short* wcvt = (unsigned short*)(m103 + NROWS); // 25 x 64 KB

    // converted-weight slots
    enum { CW_DOWN = 0, CW_MLP1W1 = 1, CW_MLP1W2 = 2, CW_W1 = 3,
           CW_PA = 4 /*4..7*/, CW_BLKW1 = 8, CW_BLKW2 = 12, CW_WI = 16,
           CW_UP = 20, CW_MLP2W1 = 21, CW_MLP2W2 = 22, CW_W2 = 23, CW_DE1 = 24 };
    PrepArgs pa;
    pa.src[CW_DOWN]   = down_w;
    pa.src[CW_MLP1W1] = mlp1_W1;
    pa.src[CW_MLP1W2] = mlp1_W2;
    pa.src[CW_W1]     = w1_W;
    for (int i = 0; i < 4; ++i) {
        pa.src[CW_PA + i]    = pa_w   + (size_t)i * NH * HIDD * VD;
        pa.src[CW_BLKW1 + i] = blk_W1 + (size_t)i * HIDD * HIDD;
        pa.src[CW_BLKW2 + i] = blk_W2 + (size_t)i * HIDD * HIDD;
        pa.src[CW_WI + i]    = wi_W   + (size_t)i * HIDD * HIDD;
    }
    pa.src[CW_UP]     = up_w;
    pa.src[CW_MLP2W1] = mlp2_W1;
    pa.src[CW_MLP2W2] = mlp2_W2;
    pa.src[CW_W2]     = w2_W;
    pa.src[CW_DE1]    = de_W1;
    pa.vwmask = (1u << CW_DOWN) | (0xFu << CW_PA) | (1u << CW_UP);

    auto CW = [&](int slot) { return wcvt + (size_t)slot * 32768; };

    dim3 b256(256), b512(512);
    dim3 gElem((NROWS * HIDD) / 256);   // 2048
    dim3 gMM(NROWS / 16);               // 256
    dim3 gAtt(NROWS / 16);              // 256 blocks x 512 thr

    auto mm = [&](const float* X, int slot, const float* bias,
                  const float* add, float* o, int g) {
        mfma_mm_kernel<<<gMM, b256, 0, stream>>>(X, CW(slot), bias, add, o,
                                                 nullptr, g);
    };
    auto attn = [&](const float* x, int vslot, const float* rv,
                    int masked, float* o) {
        mfma_mm_kernel<<<gMM, b256, 0, stream>>>(x, CW(vslot), nullptr, nullptr,
                                                 nullptr, vblk, 0);
        attn_mfma_kernel<<<gAtt, b512, 0, stream>>>(m_dist, vblk, rv,
                                                    m102, m103, o, masked);
    };
    auto dual = [&](const float* X0, int s0, const float* bias0, float* o0, int g0,
                    const float* X1, int s1, const float* bias1, float* o1, int g1) {
        mfma_mm_dual_kernel<<<dim3(512), b256, 0, stream>>>(
            X0, CW(s0), bias0, o0, g0, X1, CW(s1), bias1, o1, g1);
    };

    // weight conversion (inside launch: ws is re-poisoned before every call)
    prep_kernel<<<dim3(100), b256, 0, stream>>>(pa, wcvt);

    // percentile thresholds (used by both masked mhpas)
    percentile_kernel<<<dim3(NROWS), b256, 0, stream>>>(m_dist, m102, m103);

    // encoder
    encoder_kernel<<<gElem, b256, 0, stream>>>(inputs, en_W, en_b, ben);

    // down block: x = gelu(mlp(mhpa(en, down, loc=5)) + en@w1_W + w1_b)
    attn(ben, CW_DOWN, down_r, 1, bh);
    dual(bh, CW_MLP1W1, mlp1_b1, bt, 1,  ben, CW_W1, w1_b, br, 0);
    mm(bt, CW_MLP1W2, mlp1_b2, br, bx0, 1);

    // 4 processor blocks (ping-pong x between bx0/bx1)
    float* xin = bx0;
    float* xout = bx1;
    for (int i = 0; i < 4; ++i) {
        attn(xin, CW_PA + i, pa_r + (size_t)i * NH, 0, bh);
        dual(bh, CW_BLKW1 + i, blk_b1 + (size_t)i * HIDD, bt, 1,
             xin, CW_WI + i,   wi_b   + (size_t)i * HIDD, br, 0);
        mm(bt, CW_BLKW2 + i, blk_b2 + (size_t)i * HIDD, br, xout, 1);
        float* tmp = xin; xin = xout; xout = tmp;
    }
    // xin now holds x (== bx0 after 4 swaps)

    // up block: de = gelu(mlp(mhpa(x, up, loc=5)) + x@w2_W + w2_b)
    attn(xin, CW_UP, up_r, 1, bh);
    dual(bh, CW_MLP2W1, mlp2_b1, bt, 1,  xin, CW_W2, w2_b, br, 0);
    mm(bt, CW_MLP2W2, mlp2_b2, br, xout, 1);   // de -> xout (bx1)

    // decoder mlp
    mm(xout, CW_DE1, de_b1, nullptr, bt, 1);
    final_kernel<<<dim3(NROWS / 256), b256, 0, stream>>>(bt, de_W2, de_b2, out);
}

// Round 7
// 415.934 us; speedup vs baseline: 3.3575x; 1.1015x over previous
//
#include <hip/hip_runtime.h>
#include <cstddef>

// Problem constants
#define NROWS 4096        // B*N
#define HIDD  128
#define NH    8
#define VD    16

typedef __attribute__((ext_vector_type(8))) short bf16x8;
typedef __attribute__((ext_vector_type(4))) float f32x4;

__device__ __forceinline__ float gelu_f(float x) {
    // exact (erf) gelu, matching jax.nn.gelu(approximate=False) in fp32
    return 0.5f * x * (1.0f + erff(x * 0.70710678118654752440f));
}

__device__ __forceinline__ unsigned short bf16_rne(float f) {
    union { float f; unsigned u; } x; x.f = f;
    unsigned r = x.u + 0x7FFFu + ((x.u >> 16) & 1u);   // finite inputs only
    return (unsigned short)(r >> 16);
}
__device__ __forceinline__ float bf16_to_f(unsigned short h) {
    union { unsigned u; float f; } x; x.u = ((unsigned)h) << 16;
    return x.f;
}

__device__ __forceinline__ void split8(const float* av, bf16x8& hi, bf16x8& lo) {
    #pragma unroll
    for (int j = 0; j < 8; ++j) {
        unsigned short h = bf16_rne(av[j]);
        unsigned short l = bf16_rne(av[j] - bf16_to_f(h));
        hi[j] = (short)h; lo[j] = (short)l;
    }
}

// A-fragment loaders (verified layout A[m=lane&15][k=quad*8+jj], kt-tiled)
__device__ __forceinline__ void load_a_global(const float* __restrict__ X,
                                              int row0, int lane,
                                              bf16x8* ahi, bf16x8* alo) {
    const int q = lane >> 4, mr = lane & 15;
    const float* xr = X + (size_t)(row0 + mr) * 128 + q * 8;
    #pragma unroll
    for (int kt = 0; kt < 4; ++kt) {
        float av[8];
        *(float4*)(av)     = *(const float4*)(xr + kt * 32);
        *(float4*)(av + 4) = *(const float4*)(xr + kt * 32 + 4);
        split8(av, ahi[kt], alo[kt]);
    }
}
__device__ __forceinline__ void load_a_lds(const float (*xT)[132], int lane,
                                           bf16x8* ahi, bf16x8* alo) {
    const int q = lane >> 4, mr = lane & 15;
    #pragma unroll
    for (int kt = 0; kt < 4; ++kt) {
        float av[8];
        *(float4*)(av)     = *(const float4*)&xT[mr][kt * 32 + q * 8];
        *(float4*)(av + 4) = *(const float4*)&xT[mr][kt * 32 + q * 8 + 4];
        split8(av, ahi[kt], alo[kt]);
    }
}

// split-bf16 triple-MFMA K-step: acc += Ahi@Bhi + Ahi@Blo + Alo@Bhi
__device__ __forceinline__ f32x4 mm3(f32x4 acc, bf16x8 ahi, bf16x8 alo,
                                     const unsigned short* __restrict__ bp, int kt) {
    bf16x8 bhi = *(const bf16x8*)(bp + kt * 512);
    bf16x8 blo = *(const bf16x8*)(bp + 16384 + kt * 512);
    acc = __builtin_amdgcn_mfma_f32_16x16x32_bf16(ahi, bhi, acc, 0, 0, 0);
    acc = __builtin_amdgcn_mfma_f32_16x16x32_bf16(ahi, blo, acc, 0, 0, 0);
    acc = __builtin_amdgcn_mfma_f32_16x16x32_bf16(alo, bhi, acc, 0, 0, 0);
    return acc;
}

// store one fp32 value as bf16 into the blocked V layout read by the attn B-frag
__device__ __forceinline__ void vstore(unsigned short* __restrict__ vt,
                                       int r, int c, float v) {
    int bb = r >> 11, n = r & 2047;
    int jt = n >> 5, q2 = (n >> 3) & 3, jj = n & 7;
    int h = c >> 4, dd = c & 15;
    size_t off = (((size_t)(bb * 8 + h) * 64 + jt) * 4 + q2) * 128 + (dd << 3) + jj;
    vt[off] = bf16_rne(v);
}

// V-projection of a 16-row LDS tile into vblk (4 waves x 2 col-tiles)
__device__ __forceinline__ void vproj_lds(const float (*xT)[132], int row0,
                                          const unsigned short* __restrict__ Vw,
                                          unsigned short* __restrict__ vblk) {
    const int tid = threadIdx.x, wave = tid >> 6, lane = tid & 63;
    const int q = lane >> 4, mr = lane & 15;
    bf16x8 ahi[4], alo[4];
    load_a_lds(xT, lane, ahi, alo);
    #pragma unroll
    for (int ct = 0; ct < 2; ++ct) {
        int nt = wave * 2 + ct;
        const unsigned short* bp = Vw + (size_t)nt * 2048 + lane * 8;
        f32x4 acc = (f32x4){0.f, 0.f, 0.f, 0.f};
        #pragma unroll
        for (int kt = 0; kt < 4; ++kt) acc = mm3(acc, ahi[kt], alo[kt], bp, kt);
        int c = nt * 16 + mr;
        #pragma unroll
        for (int reg = 0; reg < 4; ++reg)
            vstore(vblk, row0 + q * 4 + reg, c, acc[reg]);
    }
}

// ---------------------------------------------------------------------------
// Weight prep + per-row 5th-percentile ranks, fused into one launch.
// Blocks 0..99: convert 25 128x128 fp32 weights into MFMA-B blocked bf16
// hi/lo planes. Blocks 100..4195: histogram-select ranks 102/103 per row.
// ---------------------------------------------------------------------------
struct PrepArgs { const float* src[25]; unsigned vwmask; };

__global__ __launch_bounds__(256) void prep_percentile_kernel(
    PrepArgs a, unsigned short* __restrict__ dst,
    const float* __restrict__ m, float* __restrict__ m102, float* __restrict__ m103)
{
    if (blockIdx.x < 100) {
        const int mat = blockIdx.x >> 2, chunk = blockIdx.x & 3;
        const float* __restrict__ W = a.src[mat];
        const int vw = (a.vwmask >> mat) & 1;
        unsigned short* __restrict__ base = dst + (size_t)mat * 32768;
        for (int o = chunk * 4096 + threadIdx.x; o < chunk * 4096 + 4096; o += 256) {
            int nt = o >> 11, kt = (o >> 9) & 3, q = (o >> 7) & 3;
            int n16 = (o >> 3) & 15, jj = o & 7;
            int k = kt * 32 + q * 8 + jj;
            float w = vw ? W[nt * 2048 + k * 16 + n16]
                         : W[k * 128 + nt * 16 + n16];
            unsigned short h = bf16_rne(w);
            unsigned short l = bf16_rne(w - bf16_to_f(h));
            base[o] = h;
            base[16384 + o] = l;
        }
        return;
    }

    __shared__ int   cnt[256];
    __shared__ int   cum[256];
    __shared__ float buf[192];
    __shared__ int   nc;
    __shared__ int   sb0, sb1, sbase;

    const int row = blockIdx.x - 100;         // 0..4095
    const int t   = threadIdx.x;
    const float* mr = m + (size_t)row * 2048;

    float4 aa = *(const float4*)(mr + t * 8);
    float4 cc = *(const float4*)(mr + t * 8 + 4);
    float v[8] = {aa.x, aa.y, aa.z, aa.w, cc.x, cc.y, cc.z, cc.w};

    cnt[t] = 0;
    if (t == 0) nc = 0;
    __syncthreads();

    int bidx[8];
    #pragma unroll
    for (int i = 0; i < 8; ++i) {
        int bi = (int)(v[i] * 256.0f);
        bi = bi < 0 ? 0 : (bi > 255 ? 255 : bi);
        bidx[i] = bi;
        atomicAdd(&cnt[bi], 1);
    }
    __syncthreads();

    if (t < 64) {
        int c0 = cnt[t * 4], c1 = cnt[t * 4 + 1], c2 = cnt[t * 4 + 2], c3 = cnt[t * 4 + 3];
        int s1 = c0 + c1, s2 = s1 + c2, s3 = s2 + c3;
        int sc = s3;
        #pragma unroll
        for (int off = 1; off < 64; off <<= 1) {
            int o = __shfl_up(sc, off);
            if (t >= off) sc += o;
        }
        int base = sc - s3;
        cum[t * 4]     = base + c0;
        cum[t * 4 + 1] = base + s1;
        cum[t * 4 + 2] = base + s2;
        cum[t * 4 + 3] = base + s3;
    }
    __syncthreads();

    {
        int cprev = (t == 0) ? 0 : cum[t - 1];
        int cthis = cum[t];
        if (cprev < 103 && 103 <= cthis) { sb0 = t; sbase = cprev; }
        if (cprev < 104 && 104 <= cthis) { sb1 = t; }
    }
    __syncthreads();

    const int b0 = sb0, b1 = sb1, base = sbase;
    #pragma unroll
    for (int i = 0; i < 8; ++i) {
        if (bidx[i] >= b0 && bidx[i] <= b1) {
            int p = atomicAdd(&nc, 1);
            if (p < 192) buf[p] = v[i];
        }
    }
    __syncthreads();

    int n = nc; if (n > 192) n = 192;
    if (t < n) {
        float x = buf[t];
        int rk = base;
        for (int j = 0; j < n; ++j) {
            float y = buf[j];
            rk += (y < x || (y == x && j < t)) ? 1 : 0;
        }
        if (rk == 102) m102[row] = x;
        if (rk == 103) m103[row] = x;
    }
}

// ---------------------------------------------------------------------------
// Encoder fused with the first V-projection: each block computes 16 rows of
// en = gelu(inputs@en_W+en_b) into LDS + global, then projects them through
// down_w into the blocked V buffer.
// ---------------------------------------------------------------------------
__global__ __launch_bounds__(256) void encoder_vproj_kernel(
    const float* __restrict__ inp, const float* __restrict__ W,
    const float* __restrict__ b, float* __restrict__ ben,
    const unsigned short* __restrict__ Vw, unsigned short* __restrict__ vblk)
{
    __shared__ float xT[16][132];
    const int tid = threadIdx.x;
    const int row0 = blockIdx.x * 16;
    const int ri = tid >> 4, c0 = (tid & 15) * 8;
    const int row = row0 + ri;
    float x0 = inp[row * 3], x1 = inp[row * 3 + 1], x2 = inp[row * 3 + 2];
    float o[8];
    #pragma unroll
    for (int j = 0; j < 8; ++j) {
        int c = c0 + j;
        o[j] = gelu_f(x0 * W[c] + x1 * W[128 + c] + x2 * W[256 + c] + b[c]);
        xT[ri][c0 + j] = o[j];
    }
    *(float4*)(ben + (size_t)row * 128 + c0)     = *(float4*)(o);
    *(float4*)(ben + (size_t)row * 128 + c0 + 4) = *(float4*)(o + 4);
    __syncthreads();
    vproj_lds(xT, row0, Vw, vblk);
}

// ---------------------------------------------------------------------------
// K1: fused MFMA flash mhpa + first MLP matmul.
// Stage 1 (validated R5/R6): block = 16 rows, 8 waves (jq x hg); masked exp
// -> bf16 A-frag; MFMA vs blocked bf16 V; partials + row-sums via LDS.
// Epilogue writes the gelu'd 16x128 mhpa tile to LDS only (bh never touches
// HBM). Stage 2: bt = gelu(bh @ W1 + b1) with A from LDS (8 waves = 8
// col-tiles), split-bf16 MFMA vs pre-blocked W1.
// ---------------------------------------------------------------------------
__global__ __launch_bounds__(512) void attn_mlp_kernel(
    const float* __restrict__ m_dist,
    const unsigned short* __restrict__ vblk,
    const float* __restrict__ rvec,
    const float* __restrict__ m102, const float* __restrict__ m103,
    const unsigned short* __restrict__ W1b, const float* __restrict__ b1,
    float* __restrict__ bt, int masked)
{
    __shared__ float partLDS[4][16][128];    // 32 KB
    __shared__ float sumLDS[4][8][16];       // 2 KB
    __shared__ float bhT[16][132];           // 8.25 KB

    const int tid  = threadIdx.x;
    const int wave = tid >> 6, lane = tid & 63;
    const int hg = wave & 1, jq = wave >> 1;       // head-group, j-quarter
    const int q = lane >> 4, rn = lane & 15;       // quad, A-row-in-tile
    const int row0 = blockIdx.x * 16;
    const int row  = row0 + rn;
    const int b    = row0 >> 11;                   // 16 | 2048 -> same batch
    const int n    = row & 2047;

    float r2[4], c2[4], thr[4];
    {
        const double pos = 5.0 / 100.0 * 2047.0;   // tfp percentile position
        const float FRAC = (float)(pos - 102.0);
        const float OM   = 1.0f - FRAC;
        float t102 = m102[row], t103 = m103[row];
        #pragma unroll
        for (int hh = 0; hh < 4; ++hh) {
            float r = rvec[hg * 4 + hh];
            r2[hh] = r * r;
            c2[hh] = -r2[hh] * 1.44269504088896340736f;  // -r^2*log2(e)
            thr[hh] = masked ? ((t102 * r2[hh]) * OM + (t103 * r2[hh]) * FRAC)
                             : 3.4028235e38f;
        }
    }

    const float* mrow = m_dist + ((size_t)b << 22) + ((size_t)n << 11);
    const unsigned short* vbase = vblk + (((size_t)(b * 8 + hg * 4)) << 15);

    f32x4 acc[4];
    #pragma unroll
    for (int hh = 0; hh < 4; ++hh) acc[hh] = (f32x4){0.f, 0.f, 0.f, 0.f};
    float rs[4] = {0.f, 0.f, 0.f, 0.f};

    for (int jt = jq * 16; jt < jq * 16 + 16; ++jt) {
        const int jb = (jt << 5) + (q << 3);
        float mv[8];
        *(float4*)(mv)     = *(const float4*)(mrow + jb);
        *(float4*)(mv + 4) = *(const float4*)(mrow + jb + 4);

        #pragma unroll
        for (int hh = 0; hh < 4; ++hh) {
            bf16x8 bfrag = *(const bf16x8*)(vbase + ((size_t)hh << 15)
                                            + ((size_t)jt << 9) + (lane << 3));
            float p[8];
            #pragma unroll
            for (int jj = 0; jj < 8; ++jj) {
                float sd = mv[jj] * r2[hh];
                float e  = exp2f(mv[jj] * c2[hh]);
                e = (sd <= thr[hh]) ? e : 0.f;
                rs[hh] += e;
                p[jj] = e;
            }
            bf16x8 afrag;
            #pragma unroll
            for (int jj = 0; jj < 8; ++jj) afrag[jj] = (short)bf16_rne(p[jj]);
            acc[hh] = __builtin_amdgcn_mfma_f32_16x16x32_bf16(afrag, bfrag,
                                                              acc[hh], 0, 0, 0);
        }
    }

    #pragma unroll
    for (int hh = 0; hh < 4; ++hh) {
        rs[hh] += __shfl_xor(rs[hh], 16);
        rs[hh] += __shfl_xor(rs[hh], 32);
    }
    if (lane < 16) {
        #pragma unroll
        for (int hh = 0; hh < 4; ++hh)
            sumLDS[jq][hg * 4 + hh][rn] = rs[hh];
    }
    #pragma unroll
    for (int hh = 0; hh < 4; ++hh) {
        #pragma unroll
        for (int reg = 0; reg < 4; ++reg)
            partLDS[jq][q * 4 + reg][(hg * 4 + hh) * 16 + rn] = acc[hh][reg];
    }
    __syncthreads();

    // epilogue -> bh tile in LDS (no global round-trip)
    {
        int e0 = tid << 2;
        int ri = e0 >> 7, c0e = e0 & 127, h = c0e >> 4;
        float4 s = *(const float4*)&partLDS[0][ri][c0e];
        #pragma unroll
        for (int k = 1; k < 4; ++k) {
            float4 pz = *(const float4*)&partLDS[k][ri][c0e];
            s.x += pz.x; s.y += pz.y; s.z += pz.z; s.w += pz.w;
        }
        float l = sumLDS[0][h][ri] + sumLDS[1][h][ri]
                + sumLDS[2][h][ri] + sumLDS[3][h][ri];
        float inv = 1.0f / l;
        float4 o;
        o.x = gelu_f(s.x * inv); o.y = gelu_f(s.y * inv);
        o.z = gelu_f(s.z * inv); o.w = gelu_f(s.w * inv);
        *(float4*)&bhT[ri][c0e] = o;
    }
    __syncthreads();

    // stage 2: bt = gelu(bh @ W1 + b1); 8 waves = 8 col-tiles
    {
        bf16x8 ahi[4], alo[4];
        load_a_lds(bhT, lane, ahi, alo);
        const unsigned short* bp = W1b + (size_t)wave * 2048 + lane * 8;
        f32x4 a2 = (f32x4){0.f, 0.f, 0.f, 0.f};
        #pragma unroll
        for (int kt = 0; kt < 4; ++kt) a2 = mm3(a2, ahi[kt], alo[kt], bp, kt);
        const int c = wave * 16 + rn;
        const float bv = b1[c];
        #pragma unroll
        for (int reg = 0; reg < 4; ++reg)
            bt[(size_t)(row0 + q * 4 + reg) * 128 + c] = gelu_f(a2[reg] + bv);
    }
}

// ---------------------------------------------------------------------------
// K2: xout = gelu(A1@B1 + bias1 + A2@B2 + bias2), then project the same 16
// rows through Vw into vblk for the next mhpa. 256 thr = 4 waves x 2 ct.
// ---------------------------------------------------------------------------
__global__ __launch_bounds__(256) void mm2_vproj_kernel(
    const float* __restrict__ A1, const unsigned short* __restrict__ B1,
    const float* __restrict__ bias1,
    const float* __restrict__ A2, const unsigned short* __restrict__ B2,
    const float* __restrict__ bias2,
    float* __restrict__ xout,
    const unsigned short* __restrict__ Vw, unsigned short* __restrict__ vblk)
{
    __shared__ float xT[16][132];
    const int tid = threadIdx.x, wave = tid >> 6, lane = tid & 63;
    const int q = lane >> 4, mr = lane & 15;
    const int row0 = blockIdx.x * 16;

    bf16x8 a1h[4], a1l[4], a2h[4], a2l[4];
    load_a_global(A1, row0, lane, a1h, a1l);
    load_a_global(A2, row0, lane, a2h, a2l);

    #pragma unroll
    for (int ct = 0; ct < 2; ++ct) {
        int nt = wave * 2 + ct;
        const unsigned short* bp1 = B1 + (size_t)nt * 2048 + lane * 8;
        const unsigned short* bp2 = B2 + (size_t)nt * 2048 + lane * 8;
        f32x4 acc = (f32x4){0.f, 0.f, 0.f, 0.f};
        #pragma unroll
        for (int kt = 0; kt < 4; ++kt) acc = mm3(acc, a1h[kt], a1l[kt], bp1, kt);
        #pragma unroll
        for (int kt = 0; kt < 4; ++kt) acc = mm3(acc, a2h[kt], a2l[kt], bp2, kt);
        int c = nt * 16 + mr;
        float bv = bias1[c] + bias2[c];
        #pragma unroll
        for (int reg = 0; reg < 4; ++reg) {
            float v = gelu_f(acc[reg] + bv);
            xout[(size_t)(row0 + q * 4 + reg) * 128 + c] = v;
            xT[q * 4 + reg][c] = v;
        }
    }
    __syncthreads();
    vproj_lds(xT, row0, Vw, vblk);
}

// ---------------------------------------------------------------------------
// Terminal K2: de = gelu(A1@B1 + A2@B2 + biases); t = gelu(de@DW1 + db1);
// out = t @ de_W2 + de_b2. de/t never leave the block.
// ---------------------------------------------------------------------------
__global__ __launch_bounds__(256) void mm2_decoder_kernel(
    const float* __restrict__ A1, const unsigned short* __restrict__ B1,
    const float* __restrict__ bias1,
    const float* __restrict__ A2, const unsigned short* __restrict__ B2,
    const float* __restrict__ bias2,
    const unsigned short* __restrict__ DW1, const float* __restrict__ db1,
    const float* __restrict__ de_W2, const float* __restrict__ de_b2,
    float* __restrict__ out)
{
    __shared__ float xT[16][132];
    __shared__ float tT[16][132];
    const int tid = threadIdx.x, wave = tid >> 6, lane = tid & 63;
    const int q = lane >> 4, mr = lane & 15;
    const int row0 = blockIdx.x * 16;

    bf16x8 a1h[4], a1l[4], a2h[4], a2l[4];
    load_a_global(A1, row0, lane, a1h, a1l);
    load_a_global(A2, row0, lane, a2h, a2l);

    #pragma unroll
    for (int ct = 0; ct < 2; ++ct) {
        int nt = wave * 2 + ct;
        const unsigned short* bp1 = B1 + (size_t)nt * 2048 + lane * 8;
        const unsigned short* bp2 = B2 + (size_t)nt * 2048 + lane * 8;
        f32x4 acc = (f32x4){0.f, 0.f, 0.f, 0.f};
        #pragma unroll
        for (int kt = 0; kt < 4; ++kt) acc = mm3(acc, a1h[kt], a1l[kt], bp1, kt);
        #pragma unroll
        for (int kt = 0; kt < 4; ++kt) acc = mm3(acc, a2h[kt], a2l[kt], bp2, kt);
        int c = nt * 16 + mr;
        float bv = bias1[c] + bias2[c];
        #pragma unroll
        for (int reg = 0; reg < 4; ++reg)
            xT[q * 4 + reg][c] = gelu_f(acc[reg] + bv);
    }
    __syncthreads();

    // t = gelu(de @ DW1 + db1)
    {
        bf16x8 ahi[4], alo[4];
        load_a_lds(xT, lane, ahi, alo);
        #pragma unroll
        for (int ct = 0; ct < 2; ++ct) {
            int nt = wave * 2 + ct;
            const unsigned short* bp = DW1 + (size_t)nt * 2048 + lane * 8;
            f32x4 acc = (f32x4){0.f, 0.f, 0.f, 0.f};
            #pragma unroll
            for (int kt = 0; kt < 4; ++kt) acc = mm3(acc, ahi[kt], alo[kt], bp, kt);
            int c = nt * 16 + mr;
            #pragma unroll
            for (int reg = 0; reg < 4; ++reg)
                tT[q * 4 + reg][c] = gelu_f(acc[reg] + db1[c]);
        }
    }
    __syncthreads();

    // out = t @ de_W2 + de_b2  (16-lane groups reduce one row each)
    {
        int r = tid >> 4, ch = tid & 15;
        const float* tp = &tT[r][ch * 8];
        const float* wp = de_W2 + ch * 8;
        float p = 0.f;
        #pragma unroll
        for (int j = 0; j < 8; ++j) p += tp[j] * wp[j];
        p += __shfl_xor(p, 1); p += __shfl_xor(p, 2);
        p += __shfl_xor(p, 4); p += __shfl_xor(p, 8);
        if (ch == 0) out[row0 + r] = p + de_b2[0];
    }
}

// ---------------------------------------------------------------------------
extern "C" void kernel_launch(void* const* d_in, const int* in_sizes, int n_in,
                              void* d_out, int out_size, void* d_ws, size_t ws_size,
                              hipStream_t stream)
{
    (void)in_sizes; (void)n_in; (void)out_size; (void)ws_size;
    const float* m_dist  = (const float*)d_in[0];
    const float* inputs  = (const float*)d_in[1];
    const float* en_W    = (const float*)d_in[2];
    const float* en_b    = (const float*)d_in[3];
    const float* down_r  = (const float*)d_in[4];
    const float* down_w  = (const float*)d_in[5];
    const float* mlp1_W1 = (const float*)d_in[6];
    const float* mlp1_b1 = (const float*)d_in[7];
    const float* mlp1_W2 = (const float*)d_in[8];
    const float* mlp1_b2 = (const float*)d_in[9];
    const float* w1_W    = (const float*)d_in[10];
    const float* w1_b    = (const float*)d_in[11];
    const float* pa_r    = (const float*)d_in[12];
    const float* pa_w    = (const float*)d_in[13];
    const float* blk_W1  = (const float*)d_in[14];
    const float* blk_b1  = (const float*)d_in[15];
    const float* blk_W2  = (const float*)d_in[16];
    const float* blk_b2  = (const float*)d_in[17];
    const float* wi_W    = (const float*)d_in[18];
    const float* wi_b    = (const float*)d_in[19];
    const float* up_r    = (const float*)d_in[20];
    const float* up_w    = (const float*)d_in[21];
    const float* mlp2_W1 = (const float*)d_in[22];
    const float* mlp2_b1 = (const float*)d_in[23];
    const float* mlp2_W2 = (const float*)d_in[24];
    const float* mlp2_b2 = (const float*)d_in[25];
    const float* w2_W    = (const float*)d_in[26];
    const float* w2_b    = (const float*)d_in[27];
    const float* de_W1   = (const float*)d_in[28];
    const float* de_b1   = (const float*)d_in[29];
    const float* de_W2   = (const float*)d_in[30];
    const float* de_b2   = (const float*)d_in[31];
    float* out = (float*)d_out;

    // workspace layout (floats)
    const size_t BUF = (size_t)NROWS * HIDD;   // 524288
    float* w     = (float*)d_ws;
    float* ben   = w;
    float* bx0   = w + 1 * BUF;
    float* bx1   = w + 2 * BUF;
    float* bt    = w + 3 * BUF;
    unsigned short* vblk = (unsigned short*)(w + 4 * BUF);  // 1 MB bf16 blocked V
    float* m102  = w + 5 * BUF;
    float* m103  = m102 + NROWS;
    unsigned short* wcvt = (unsigned short*)(m103 + NROWS); // 25 x 64 KB

    enum { CW_DOWN = 0, CW_MLP1W1 = 1, CW_MLP1W2 = 2, CW_W1 = 3,
           CW_PA = 4 /*4..7*/, CW_BLKW1 = 8, CW_BLKW2 = 12, CW_WI = 16,
           CW_UP = 20, CW_MLP2W1 = 21, CW_MLP2W2 = 22, CW_W2 = 23, CW_DE1 = 24 };
    PrepArgs pa;
    pa.src[CW_DOWN]   = down_w;
    pa.src[CW_MLP1W1] = mlp1_W1;
    pa.src[CW_MLP1W2] = mlp1_W2;
    pa.src[CW_W1]     = w1_W;
    for (int i = 0; i < 4; ++i) {
        pa.src[CW_PA + i]    = pa_w   + (size_t)i * NH * HIDD * VD;
        pa.src[CW_BLKW1 + i] = blk_W1 + (size_t)i * HIDD * HIDD;
        pa.src[CW_BLKW2 + i] = blk_W2 + (size_t)i * HIDD * HIDD;
        pa.src[CW_WI + i]    = wi_W   + (size_t)i * HIDD * HIDD;
    }
    pa.src[CW_UP]     = up_w;
    pa.src[CW_MLP2W1] = mlp2_W1;
    pa.src[CW_MLP2W2] = mlp2_W2;
    pa.src[CW_W2]     = w2_W;
    pa.src[CW_DE1]    = de_W1;
    pa.vwmask = (1u << CW_DOWN) | (0xFu << CW_PA) | (1u << CW_UP);

    auto CW = [&](int slot) { return wcvt + (size_t)slot * 32768; };

    dim3 b256(256), b512(512);
    dim3 gT(NROWS / 16);                // 256 tile-blocks

    auto K1 = [&](const float* rv, int masked, int w1slot, const float* b1v) {
        attn_mlp_kernel<<<gT, b512, 0, stream>>>(m_dist, vblk, rv, m102, m103,
                                                 CW(w1slot), b1v, bt, masked);
    };
    auto K2 = [&](int s1, const float* bias1, const float* A2, int s2,
                  const float* bias2, float* xo, int vslot) {
        mm2_vproj_kernel<<<gT, b256, 0, stream>>>(bt, CW(s1), bias1,
                                                  A2, CW(s2), bias2,
                                                  xo, CW(vslot), vblk);
    };

    // weight prep + percentile thresholds (one launch)
    prep_percentile_kernel<<<dim3(100 + NROWS), b256, 0, stream>>>(
        pa, wcvt, m_dist, m102, m103);

    // encoder + V-projection for the down mhpa
    encoder_vproj_kernel<<<gT, b256, 0, stream>>>(inputs, en_W, en_b, ben,
                                                  CW(CW_DOWN), vblk);

    // down block
    K1(down_r, 1, CW_MLP1W1, mlp1_b1);
    K2(CW_MLP1W2, mlp1_b2, ben, CW_W1, w1_b, bx0, CW_PA + 0);

    // 4 processor blocks (ping-pong bx0/bx1)
    float* xin = bx0;
    float* xout = bx1;
    for (int i = 0; i < 4; ++i) {
        K1(pa_r + (size_t)i * NH, 0, CW_BLKW1 + i, blk_b1 + (size_t)i * HIDD);
        K2(CW_BLKW2 + i, blk_b2 + (size_t)i * HIDD,
           xin, CW_WI + i, wi_b + (size_t)i * HIDD,
           xout, (i < 3) ? (CW_PA + i + 1) : CW_UP);
        float* tmp = xin; xin = xout; xout = tmp;
    }
    // xin now holds x

    // up block + decoder + final (terminal fused kernel)
    K1(up_r, 1, CW_MLP2W1, mlp2_b1);
    mm2_decoder_kernel<<<gT, b256, 0, stream>>>(
        bt, CW(CW_MLP2W2), mlp2_b2,
        xin, CW(CW_W2), w2_b,
        CW(CW_DE1), de_b1, de_W2, de_b2, out);
}

// Round 8
// 317.903 us; speedup vs baseline: 4.3928x; 1.3084x over previous
//
#include <hip/hip_runtime.h>
#include <hip/hip_bf16.h>
#include <cstddef>

// Problem constants
#define NROWS 4096        // B*N
#define HIDD  128
#define NH    8
#define VD    16

typedef __attribute__((ext_vector_type(8))) short bf16x8;
typedef __attribute__((ext_vector_type(4))) float f32x4;
typedef __attribute__((ext_vector_type(4))) unsigned int u32x4;

__device__ __forceinline__ float gelu_f(float x) {
    // exact (erf) gelu, matching jax.nn.gelu(approximate=False) in fp32
    return 0.5f * x * (1.0f + erff(x * 0.70710678118654752440f));
}

__device__ __forceinline__ unsigned short bf16_rne(float f) {
    union { float f; unsigned u; } x; x.f = f;
    unsigned r = x.u + 0x7FFFu + ((x.u >> 16) & 1u);   // finite inputs only
    return (unsigned short)(r >> 16);
}
__device__ __forceinline__ float bf16_to_f(unsigned short h) {
    union { unsigned u; float f; } x; x.u = ((unsigned)h) << 16;
    return x.f;
}
// packed RNE f32x2 -> bf16x2 (v_cvt_pk path; bit-identical to bf16_rne)
__device__ __forceinline__ unsigned pk_bf16(float a, float b) {
    __hip_bfloat162 t = __float22bfloat162_rn(make_float2(a, b));
    unsigned u; __builtin_memcpy(&u, &t, 4); return u;
}

__device__ __forceinline__ void split8(const float* av, bf16x8& hi, bf16x8& lo) {
    #pragma unroll
    for (int j = 0; j < 8; ++j) {
        unsigned short h = bf16_rne(av[j]);
        unsigned short l = bf16_rne(av[j] - bf16_to_f(h));
        hi[j] = (short)h; lo[j] = (short)l;
    }
}

// A-fragment loaders (verified layout A[m=lane&15][k=quad*8+jj], kt-tiled)
__device__ __forceinline__ void load_a_global(const float* __restrict__ X,
                                              int row0, int lane,
                                              bf16x8* ahi, bf16x8* alo) {
    const int q = lane >> 4, mr = lane & 15;
    const float* xr = X + (size_t)(row0 + mr) * 128 + q * 8;
    #pragma unroll
    for (int kt = 0; kt < 4; ++kt) {
        float av[8];
        *(float4*)(av)     = *(const float4*)(xr + kt * 32);
        *(float4*)(av + 4) = *(const float4*)(xr + kt * 32 + 4);
        split8(av, ahi[kt], alo[kt]);
    }
}
__device__ __forceinline__ void load_a_lds(const float (*xT)[132], int lane,
                                           bf16x8* ahi, bf16x8* alo) {
    const int q = lane >> 4, mr = lane & 15;
    #pragma unroll
    for (int kt = 0; kt < 4; ++kt) {
        float av[8];
        *(float4*)(av)     = *(const float4*)&xT[mr][kt * 32 + q * 8];
        *(float4*)(av + 4) = *(const float4*)&xT[mr][kt * 32 + q * 8 + 4];
        split8(av, ahi[kt], alo[kt]);
    }
}

// split-bf16 triple-MFMA K-step: acc += Ahi@Bhi + Ahi@Blo + Alo@Bhi
__device__ __forceinline__ f32x4 mm3(f32x4 acc, bf16x8 ahi, bf16x8 alo,
                                     const unsigned short* __restrict__ bp, int kt) {
    bf16x8 bhi = *(const bf16x8*)(bp + kt * 512);
    bf16x8 blo = *(const bf16x8*)(bp + 16384 + kt * 512);
    acc = __builtin_amdgcn_mfma_f32_16x16x32_bf16(ahi, bhi, acc, 0, 0, 0);
    acc = __builtin_amdgcn_mfma_f32_16x16x32_bf16(ahi, blo, acc, 0, 0, 0);
    acc = __builtin_amdgcn_mfma_f32_16x16x32_bf16(alo, bhi, acc, 0, 0, 0);
    return acc;
}

// store one fp32 value as bf16 into the blocked V layout read by the attn B-frag
__device__ __forceinline__ void vstore(unsigned short* __restrict__ vt,
                                       int r, int c, float v) {
    int bb = r >> 11, n = r & 2047;
    int jt = n >> 5, q2 = (n >> 3) & 3, jj = n & 7;
    int h = c >> 4, dd = c & 15;
    size_t off = (((size_t)(bb * 8 + h) * 64 + jt) * 4 + q2) * 128 + (dd << 3) + jj;
    vt[off] = bf16_rne(v);
}

// V-projection of a 16-row LDS tile into vblk (4 waves x 2 col-tiles)
__device__ __forceinline__ void vproj_lds(const float (*xT)[132], int row0,
                                          const unsigned short* __restrict__ Vw,
                                          unsigned short* __restrict__ vblk) {
    const int tid = threadIdx.x, wave = tid >> 6, lane = tid & 63;
    const int q = lane >> 4, mr = lane & 15;
    bf16x8 ahi[4], alo[4];
    load_a_lds(xT, lane, ahi, alo);
    #pragma unroll
    for (int ct = 0; ct < 2; ++ct) {
        int nt = wave * 2 + ct;
        const unsigned short* bp = Vw + (size_t)nt * 2048 + lane * 8;
        f32x4 acc = (f32x4){0.f, 0.f, 0.f, 0.f};
        #pragma unroll
        for (int kt = 0; kt < 4; ++kt) acc = mm3(acc, ahi[kt], alo[kt], bp, kt);
        int c = nt * 16 + mr;
        #pragma unroll
        for (int reg = 0; reg < 4; ++reg)
            vstore(vblk, row0 + q * 4 + reg, c, acc[reg]);
    }
}

// ---------------------------------------------------------------------------
// Weight prep + per-row 5th-percentile ranks, fused into one launch.
// ---------------------------------------------------------------------------
struct PrepArgs { const float* src[25]; unsigned vwmask; };

__global__ __launch_bounds__(256) void prep_percentile_kernel(
    PrepArgs a, unsigned short* __restrict__ dst,
    const float* __restrict__ m, float* __restrict__ m102, float* __restrict__ m103)
{
    if (blockIdx.x < 100) {
        const int mat = blockIdx.x >> 2, chunk = blockIdx.x & 3;
        const float* __restrict__ W = a.src[mat];
        const int vw = (a.vwmask >> mat) & 1;
        unsigned short* __restrict__ base = dst + (size_t)mat * 32768;
        for (int o = chunk * 4096 + threadIdx.x; o < chunk * 4096 + 4096; o += 256) {
            int nt = o >> 11, kt = (o >> 9) & 3, q = (o >> 7) & 3;
            int n16 = (o >> 3) & 15, jj = o & 7;
            int k = kt * 32 + q * 8 + jj;
            float w = vw ? W[nt * 2048 + k * 16 + n16]
                         : W[k * 128 + nt * 16 + n16];
            unsigned short h = bf16_rne(w);
            unsigned short l = bf16_rne(w - bf16_to_f(h));
            base[o] = h;
            base[16384 + o] = l;
        }
        return;
    }

    __shared__ int   cnt[256];
    __shared__ int   cum[256];
    __shared__ float buf[192];
    __shared__ int   nc;
    __shared__ int   sb0, sb1, sbase;

    const int row = blockIdx.x - 100;         // 0..4095
    const int t   = threadIdx.x;
    const float* mr = m + (size_t)row * 2048;

    float4 aa = *(const float4*)(mr + t * 8);
    float4 cc = *(const float4*)(mr + t * 8 + 4);
    float v[8] = {aa.x, aa.y, aa.z, aa.w, cc.x, cc.y, cc.z, cc.w};

    cnt[t] = 0;
    if (t == 0) nc = 0;
    __syncthreads();

    int bidx[8];
    #pragma unroll
    for (int i = 0; i < 8; ++i) {
        int bi = (int)(v[i] * 256.0f);
        bi = bi < 0 ? 0 : (bi > 255 ? 255 : bi);
        bidx[i] = bi;
        atomicAdd(&cnt[bi], 1);
    }
    __syncthreads();

    if (t < 64) {
        int c0 = cnt[t * 4], c1 = cnt[t * 4 + 1], c2 = cnt[t * 4 + 2], c3 = cnt[t * 4 + 3];
        int s1 = c0 + c1, s2 = s1 + c2, s3 = s2 + c3;
        int sc = s3;
        #pragma unroll
        for (int off = 1; off < 64; off <<= 1) {
            int o = __shfl_up(sc, off);
            if (t >= off) sc += o;
        }
        int base = sc - s3;
        cum[t * 4]     = base + c0;
        cum[t * 4 + 1] = base + s1;
        cum[t * 4 + 2] = base + s2;
        cum[t * 4 + 3] = base + s3;
    }
    __syncthreads();

    {
        int cprev = (t == 0) ? 0 : cum[t - 1];
        int cthis = cum[t];
        if (cprev < 103 && 103 <= cthis) { sb0 = t; sbase = cprev; }
        if (cprev < 104 && 104 <= cthis) { sb1 = t; }
    }
    __syncthreads();

    const int b0 = sb0, b1 = sb1, base = sbase;
    #pragma unroll
    for (int i = 0; i < 8; ++i) {
        if (bidx[i] >= b0 && bidx[i] <= b1) {
            int p = atomicAdd(&nc, 1);
            if (p < 192) buf[p] = v[i];
        }
    }
    __syncthreads();

    int n = nc; if (n > 192) n = 192;
    if (t < n) {
        float x = buf[t];
        int rk = base;
        for (int j = 0; j < n; ++j) {
            float y = buf[j];
            rk += (y < x || (y == x && j < t)) ? 1 : 0;
        }
        if (rk == 102) m102[row] = x;
        if (rk == 103) m103[row] = x;
    }
}

// ---------------------------------------------------------------------------
// Encoder fused with the first V-projection.
// ---------------------------------------------------------------------------
__global__ __launch_bounds__(256) void encoder_vproj_kernel(
    const float* __restrict__ inp, const float* __restrict__ W,
    const float* __restrict__ b, float* __restrict__ ben,
    const unsigned short* __restrict__ Vw, unsigned short* __restrict__ vblk)
{
    __shared__ float xT[16][132];
    const int tid = threadIdx.x;
    const int row0 = blockIdx.x * 16;
    const int ri = tid >> 4, c0 = (tid & 15) * 8;
    const int row = row0 + ri;
    float x0 = inp[row * 3], x1 = inp[row * 3 + 1], x2 = inp[row * 3 + 2];
    float o[8];
    #pragma unroll
    for (int j = 0; j < 8; ++j) {
        int c = c0 + j;
        o[j] = gelu_f(x0 * W[c] + x1 * W[128 + c] + x2 * W[256 + c] + b[c]);
        xT[ri][c0 + j] = o[j];
    }
    *(float4*)(ben + (size_t)row * 128 + c0)     = *(float4*)(o);
    *(float4*)(ben + (size_t)row * 128 + c0 + 4) = *(float4*)(o + 4);
    __syncthreads();
    vproj_lds(xT, row0, Vw, vblk);
}

// ---------------------------------------------------------------------------
// K1: fused MFMA flash mhpa + first MLP matmul — R8 software-pipelined.
// Per jt iteration: prefetch jt+1's m-float4s + 4 V-fragments (registers),
// compute masked exp (single v_exp_f32) -> packed bf16 A-frag -> MFMA vs V
// and vs an all-ones B (row-sums in MFMA accumulators, replacing 32 scalar
// adds + butterfly). Separate unmasked loop drops the threshold compare.
// ---------------------------------------------------------------------------
__global__ __launch_bounds__(512) void attn_mlp_kernel(
    const float* __restrict__ m_dist,
    const unsigned short* __restrict__ vblk,
    const float* __restrict__ rvec,
    const float* __restrict__ m102, const float* __restrict__ m103,
    const unsigned short* __restrict__ W1b, const float* __restrict__ b1,
    float* __restrict__ bt, int masked)
{
    __shared__ float partLDS[4][16][128];    // 32 KB
    __shared__ float sumLDS[4][8][16];       // 2 KB
    __shared__ float bhT[16][132];           // 8.25 KB

    const int tid  = threadIdx.x;
    const int wave = tid >> 6, lane = tid & 63;
    const int hg = wave & 1, jq = wave >> 1;       // head-group, j-quarter
    const int q = lane >> 4, rn = lane & 15;       // quad, A-row-in-tile
    const int row0 = blockIdx.x * 16;
    const int row  = row0 + rn;
    const int b    = row0 >> 11;                   // 16 | 2048 -> same batch
    const int n    = row & 2047;

    float r2[4], c2[4], thr[4];
    {
        const double pos = 5.0 / 100.0 * 2047.0;   // tfp percentile position
        const float FRAC = (float)(pos - 102.0);
        const float OM   = 1.0f - FRAC;
        float t102 = m102[row], t103 = m103[row];
        #pragma unroll
        for (int hh = 0; hh < 4; ++hh) {
            float r = rvec[hg * 4 + hh];
            r2[hh] = r * r;
            c2[hh] = -r2[hh] * 1.44269504088896340736f;  // -r^2*log2(e)
            thr[hh] = masked ? ((t102 * r2[hh]) * OM + (t103 * r2[hh]) * FRAC)
                             : 3.4028235e38f;
        }
    }

    const float* mrow = m_dist + ((size_t)b << 22) + ((size_t)n << 11);
    const unsigned short* vbase = vblk + (((size_t)(b * 8 + hg * 4)) << 15);

    f32x4 acc[4], accs[4];
    #pragma unroll
    for (int hh = 0; hh < 4; ++hh) {
        acc[hh]  = (f32x4){0.f, 0.f, 0.f, 0.f};
        accs[hh] = (f32x4){0.f, 0.f, 0.f, 0.f};
    }
    bf16x8 vones;
    #pragma unroll
    for (int j = 0; j < 8; ++j) vones[j] = (short)0x3F80;   // bf16 1.0

    const int jbeg = jq * 16, jend = jbeg + 16;
    float mv[8]; bf16x8 bfr[4];
    {
        const int jb = (jbeg << 5) + (q << 3);
        *(float4*)(mv)     = *(const float4*)(mrow + jb);
        *(float4*)(mv + 4) = *(const float4*)(mrow + jb + 4);
        #pragma unroll
        for (int hh = 0; hh < 4; ++hh)
            bfr[hh] = *(const bf16x8*)(vbase + ((size_t)hh << 15)
                                        + ((size_t)jbeg << 9) + (lane << 3));
    }

    if (masked) {
        for (int jt = jbeg; jt < jend; ++jt) {
            const int jn = (jt + 1 < jend) ? jt + 1 : jt;   // clamped prefetch
            float mvn[8]; bf16x8 bfn[4];
            const int jbn = (jn << 5) + (q << 3);
            *(float4*)(mvn)     = *(const float4*)(mrow + jbn);
            *(float4*)(mvn + 4) = *(const float4*)(mrow + jbn + 4);
            #pragma unroll
            for (int hh = 0; hh < 4; ++hh)
                bfn[hh] = *(const bf16x8*)(vbase + ((size_t)hh << 15)
                                            + ((size_t)jn << 9) + (lane << 3));

            #pragma unroll
            for (int hh = 0; hh < 4; ++hh) {
                float p[8];
                #pragma unroll
                for (int jj = 0; jj < 8; ++jj) {
                    float sd = mv[jj] * r2[hh];
                    float e  = __builtin_amdgcn_exp2f(mv[jj] * c2[hh]);
                    p[jj] = (sd <= thr[hh]) ? e : 0.f;
                }
                u32x4 af;
                af[0] = pk_bf16(p[0], p[1]); af[1] = pk_bf16(p[2], p[3]);
                af[2] = pk_bf16(p[4], p[5]); af[3] = pk_bf16(p[6], p[7]);
                bf16x8 afrag = __builtin_bit_cast(bf16x8, af);
                acc[hh]  = __builtin_amdgcn_mfma_f32_16x16x32_bf16(afrag, bfr[hh], acc[hh], 0, 0, 0);
                accs[hh] = __builtin_amdgcn_mfma_f32_16x16x32_bf16(afrag, vones,   accs[hh], 0, 0, 0);
            }
            #pragma unroll
            for (int jj = 0; jj < 8; ++jj) mv[jj] = mvn[jj];
            #pragma unroll
            for (int hh = 0; hh < 4; ++hh) bfr[hh] = bfn[hh];
        }
    } else {
        for (int jt = jbeg; jt < jend; ++jt) {
            const int jn = (jt + 1 < jend) ? jt + 1 : jt;
            float mvn[8]; bf16x8 bfn[4];
            const int jbn = (jn << 5) + (q << 3);
            *(float4*)(mvn)     = *(const float4*)(mrow + jbn);
            *(float4*)(mvn + 4) = *(const float4*)(mrow + jbn + 4);
            #pragma unroll
            for (int hh = 0; hh < 4; ++hh)
                bfn[hh] = *(const bf16x8*)(vbase + ((size_t)hh << 15)
                                            + ((size_t)jn << 9) + (lane << 3));

            #pragma unroll
            for (int hh = 0; hh < 4; ++hh) {
                float p[8];
                #pragma unroll
                for (int jj = 0; jj < 8; ++jj)
                    p[jj] = __builtin_amdgcn_exp2f(mv[jj] * c2[hh]);
                u32x4 af;
                af[0] = pk_bf16(p[0], p[1]); af[1] = pk_bf16(p[2], p[3]);
                af[2] = pk_bf16(p[4], p[5]); af[3] = pk_bf16(p[6], p[7]);
                bf16x8 afrag = __builtin_bit_cast(bf16x8, af);
                acc[hh]  = __builtin_amdgcn_mfma_f32_16x16x32_bf16(afrag, bfr[hh], acc[hh], 0, 0, 0);
                accs[hh] = __builtin_amdgcn_mfma_f32_16x16x32_bf16(afrag, vones,   accs[hh], 0, 0, 0);
            }
            #pragma unroll
            for (int jj = 0; jj < 8; ++jj) mv[jj] = mvn[jj];
            #pragma unroll
            for (int hh = 0; hh < 4; ++hh) bfr[hh] = bfn[hh];
        }
    }

    // row-sums: accs D-layout row = q*4+reg (value replicated across cols);
    // col-0 lanes (rn==0, q=0..3) cover all 16 tile rows.
    if (rn == 0) {
        #pragma unroll
        for (int hh = 0; hh < 4; ++hh)
            #pragma unroll
            for (int reg = 0; reg < 4; ++reg)
                sumLDS[jq][hg * 4 + hh][q * 4 + reg] = accs[hh][reg];
    }
    #pragma unroll
    for (int hh = 0; hh < 4; ++hh) {
        #pragma unroll
        for (int reg = 0; reg < 4; ++reg)
            partLDS[jq][q * 4 + reg][(hg * 4 + hh) * 16 + rn] = acc[hh][reg];
    }
    __syncthreads();

    // epilogue -> bh tile in LDS (no global round-trip)
    {
        int e0 = tid << 2;
        int ri = e0 >> 7, c0e = e0 & 127, h = c0e >> 4;
        float4 s = *(const float4*)&partLDS[0][ri][c0e];
        #pragma unroll
        for (int k = 1; k < 4; ++k) {
            float4 pz = *(const float4*)&partLDS[k][ri][c0e];
            s.x += pz.x; s.y += pz.y; s.z += pz.z; s.w += pz.w;
        }
        float l = sumLDS[0][h][ri] + sumLDS[1][h][ri]
                + sumLDS[2][h][ri] + sumLDS[3][h][ri];
        float inv = 1.0f / l;
        float4 o;
        o.x = gelu_f(s.x * inv); o.y = gelu_f(s.y * inv);
        o.z = gelu_f(s.z * inv); o.w = gelu_f(s.w * inv);
        *(float4*)&bhT[ri][c0e] = o;
    }
    __syncthreads();

    // stage 2: bt = gelu(bh @ W1 + b1); 8 waves = 8 col-tiles
    {
        bf16x8 ahi[4], alo[4];
        load_a_lds(bhT, lane, ahi, alo);
        const unsigned short* bp = W1b + (size_t)wave * 2048 + lane * 8;
        f32x4 a2 = (f32x4){0.f, 0.f, 0.f, 0.f};
        #pragma unroll
        for (int kt = 0; kt < 4; ++kt) a2 = mm3(a2, ahi[kt], alo[kt], bp, kt);
        const int c = wave * 16 + rn;
        const float bv = b1[c];
        #pragma unroll
        for (int reg = 0; reg < 4; ++reg)
            bt[(size_t)(row0 + q * 4 + reg) * 128 + c] = gelu_f(a2[reg] + bv);
    }
}

// ---------------------------------------------------------------------------
// K2: xout = gelu(A1@B1 + bias1 + A2@B2 + bias2), then project the same 16
// rows through Vw into vblk for the next mhpa. 256 thr = 4 waves x 2 ct.
// ---------------------------------------------------------------------------
__global__ __launch_bounds__(256) void mm2_vproj_kernel(
    const float* __restrict__ A1, const unsigned short* __restrict__ B1,
    const float* __restrict__ bias1,
    const float* __restrict__ A2, const unsigned short* __restrict__ B2,
    const float* __restrict__ bias2,
    float* __restrict__ xout,
    const unsigned short* __restrict__ Vw, unsigned short* __restrict__ vblk)
{
    __shared__ float xT[16][132];
    const int tid = threadIdx.x, wave = tid >> 6, lane = tid & 63;
    const int q = lane >> 4, mr = lane & 15;
    const int row0 = blockIdx.x * 16;

    bf16x8 a1h[4], a1l[4], a2h[4], a2l[4];
    load_a_global(A1, row0, lane, a1h, a1l);
    load_a_global(A2, row0, lane, a2h, a2l);

    #pragma unroll
    for (int ct = 0; ct < 2; ++ct) {
        int nt = wave * 2 + ct;
        const unsigned short* bp1 = B1 + (size_t)nt * 2048 + lane * 8;
        const unsigned short* bp2 = B2 + (size_t)nt * 2048 + lane * 8;
        f32x4 acc = (f32x4){0.f, 0.f, 0.f, 0.f};
        #pragma unroll
        for (int kt = 0; kt < 4; ++kt) acc = mm3(acc, a1h[kt], a1l[kt], bp1, kt);
        #pragma unroll
        for (int kt = 0; kt < 4; ++kt) acc = mm3(acc, a2h[kt], a2l[kt], bp2, kt);
        int c = nt * 16 + mr;
        float bv = bias1[c] + bias2[c];
        #pragma unroll
        for (int reg = 0; reg < 4; ++reg) {
            float v = gelu_f(acc[reg] + bv);
            xout[(size_t)(row0 + q * 4 + reg) * 128 + c] = v;
            xT[q * 4 + reg][c] = v;
        }
    }
    __syncthreads();
    vproj_lds(xT, row0, Vw, vblk);
}

// ---------------------------------------------------------------------------
// Terminal K2: de = gelu(A1@B1 + A2@B2 + biases); t = gelu(de@DW1 + db1);
// out = t @ de_W2 + de_b2. de/t never leave the block.
// ---------------------------------------------------------------------------
__global__ __launch_bounds__(256) void mm2_decoder_kernel(
    const float* __restrict__ A1, const unsigned short* __restrict__ B1,
    const float* __restrict__ bias1,
    const float* __restrict__ A2, const unsigned short* __restrict__ B2,
    const float* __restrict__ bias2,
    const unsigned short* __restrict__ DW1, const float* __restrict__ db1,
    const float* __restrict__ de_W2, const float* __restrict__ de_b2,
    float* __restrict__ out)
{
    __shared__ float xT[16][132];
    __shared__ float tT[16][132];
    const int tid = threadIdx.x, wave = tid >> 6, lane = tid & 63;
    const int q = lane >> 4, mr = lane & 15;
    const int row0 = blockIdx.x * 16;

    bf16x8 a1h[4], a1l[4], a2h[4], a2l[4];
    load_a_global(A1, row0, lane, a1h, a1l);
    load_a_global(A2, row0, lane, a2h, a2l);

    #pragma unroll
    for (int ct = 0; ct < 2; ++ct) {
        int nt = wave * 2 + ct;
        const unsigned short* bp1 = B1 + (size_t)nt * 2048 + lane * 8;
        const unsigned short* bp2 = B2 + (size_t)nt * 2048 + lane * 8;
        f32x4 acc = (f32x4){0.f, 0.f, 0.f, 0.f};
        #pragma unroll
        for (int kt = 0; kt < 4; ++kt) acc = mm3(acc, a1h[kt], a1l[kt], bp1, kt);
        #pragma unroll
        for (int kt = 0; kt < 4; ++kt) acc = mm3(acc, a2h[kt], a2l[kt], bp2, kt);
        int c = nt * 16 + mr;
        float bv = bias1[c] + bias2[c];
        #pragma unroll
        for (int reg = 0; reg < 4; ++reg)
            xT[q * 4 + reg][c] = gelu_f(acc[reg] + bv);
    }
    __syncthreads();

    // t = gelu(de @ DW1 + db1)
    {
        bf16x8 ahi[4], alo[4];
        load_a_lds(xT, lane, ahi, alo);
        #pragma unroll
        for (int ct = 0; ct < 2; ++ct) {
            int nt = wave * 2 + ct;
            const unsigned short* bp = DW1 + (size_t)nt * 2048 + lane * 8;
            f32x4 acc = (f32x4){0.f, 0.f, 0.f, 0.f};
            #pragma unroll
            for (int kt = 0; kt < 4; ++kt) acc = mm3(acc, ahi[kt], alo[kt], bp, kt);
            int c = nt * 16 + mr;
            #pragma unroll
            for (int reg = 0; reg < 4; ++reg)
                tT[q * 4 + reg][c] = gelu_f(acc[reg] + db1[c]);
        }
    }
    __syncthreads();

    // out = t @ de_W2 + de_b2  (16-lane groups reduce one row each)
    {
        int r = tid >> 4, ch = tid & 15;
        const float* tp = &tT[r][ch * 8];
        const float* wp = de_W2 + ch * 8;
        float p = 0.f;
        #pragma unroll
        for (int j = 0; j < 8; ++j) p += tp[j] * wp[j];
        p += __shfl_xor(p, 1); p += __shfl_xor(p, 2);
        p += __shfl_xor(p, 4); p += __shfl_xor(p, 8);
        if (ch == 0) out[row0 + r] = p + de_b2[0];
    }
}

// ---------------------------------------------------------------------------
extern "C" void kernel_launch(void* const* d_in, const int* in_sizes, int n_in,
                              void* d_out, int out_size, void* d_ws, size_t ws_size,
                              hipStream_t stream)
{
    (void)in_sizes; (void)n_in; (void)out_size; (void)ws_size;
    const float* m_dist  = (const float*)d_in[0];
    const float* inputs  = (const float*)d_in[1];
    const float* en_W    = (const float*)d_in[2];
    const float* en_b    = (const float*)d_in[3];
    const float* down_r  = (const float*)d_in[4];
    const float* down_w  = (const float*)d_in[5];
    const float* mlp1_W1 = (const float*)d_in[6];
    const float* mlp1_b1 = (const float*)d_in[7];
    const float* mlp1_W2 = (const float*)d_in[8];
    const float* mlp1_b2 = (const float*)d_in[9];
    const float* w1_W    = (const float*)d_in[10];
    const float* w1_b    = (const float*)d_in[11];
    const float* pa_r    = (const float*)d_in[12];
    const float* pa_w    = (const float*)d_in[13];
    const float* blk_W1  = (const float*)d_in[14];
    const float* blk_b1  = (const float*)d_in[15];
    const float* blk_W2  = (const float*)d_in[16];
    const float* blk_b2  = (const float*)d_in[17];
    const float* wi_W    = (const float*)d_in[18];
    const float* wi_b    = (const float*)d_in[19];
    const float* up_r    = (const float*)d_in[20];
    const float* up_w    = (const float*)d_in[21];
    const float* mlp2_W1 = (const float*)d_in[22];
    const float* mlp2_b1 = (const float*)d_in[23];
    const float* mlp2_W2 = (const float*)d_in[24];
    const float* mlp2_b2 = (const float*)d_in[25];
    const float* w2_W    = (const float*)d_in[26];
    const float* w2_b    = (const float*)d_in[27];
    const float* de_W1   = (const float*)d_in[28];
    const float* de_b1   = (const float*)d_in[29];
    const float* de_W2   = (const float*)d_in[30];
    const float* de_b2   = (const float*)d_in[31];
    float* out = (float*)d_out;

    // workspace layout (floats)
    const size_t BUF = (size_t)NROWS * HIDD;   // 524288
    float* w     = (float*)d_ws;
    float* ben   = w;
    float* bx0   = w + 1 * BUF;
    float* bx1   = w + 2 * BUF;
    float* bt    = w + 3 * BUF;
    unsigned short* vblk = (unsigned short*)(w + 4 * BUF);  // 1 MB bf16 blocked V
    float* m102  = w + 5 * BUF;
    float* m103  = m102 + NROWS;
    unsigned short* wcvt = (unsigned short*)(m103 + NROWS); // 25 x 64 KB

    enum { CW_DOWN = 0, CW_MLP1W1 = 1, CW_MLP1W2 = 2, CW_W1 = 3,
           CW_PA = 4 /*4..7*/, CW_BLKW1 = 8, CW_BLKW2 = 12, CW_WI = 16,
           CW_UP = 20, CW_MLP2W1 = 21, CW_MLP2W2 = 22, CW_W2 = 23, CW_DE1 = 24 };
    PrepArgs pa;
    pa.src[CW_DOWN]   = down_w;
    pa.src[CW_MLP1W1] = mlp1_W1;
    pa.src[CW_MLP1W2] = mlp1_W2;
    pa.src[CW_W1]     = w1_W;
    for (int i = 0; i < 4; ++i) {
        pa.src[CW_PA + i]    = pa_w   + (size_t)i * NH * HIDD * VD;
        pa.src[CW_BLKW1 + i] = blk_W1 + (size_t)i * HIDD * HIDD;
        pa.src[CW_BLKW2 + i] = blk_W2 + (size_t)i * HIDD * HIDD;
        pa.src[CW_WI + i]    = wi_W   + (size_t)i * HIDD * HIDD;
    }
    pa.src[CW_UP]     = up_w;
    pa.src[CW_MLP2W1] = mlp2_W1;
    pa.src[CW_MLP2W2] = mlp2_W2;
    pa.src[CW_W2]     = w2_W;
    pa.src[CW_DE1]    = de_W1;
    pa.vwmask = (1u << CW_DOWN) | (0xFu << CW_PA) | (1u << CW_UP);

    auto CW = [&](int slot) { return wcvt + (size_t)slot * 32768; };

    dim3 b256(256), b512(512);
    dim3 gT(NROWS / 16);                // 256 tile-blocks

    auto K1 = [&](const float* rv, int masked, int w1slot, const float* b1v) {
        attn_mlp_kernel<<<gT, b512, 0, stream>>>(m_dist, vblk, rv, m102, m103,
                                                 CW(w1slot), b1v, bt, masked);
    };
    auto K2 = [&](int s1, const float* bias1, const float* A2, int s2,
                  const float* bias2, float* xo, int vslot) {
        mm2_vproj_kernel<<<gT, b256, 0, stream>>>(bt, CW(s1), bias1,
                                                  A2, CW(s2), bias2,
                                                  xo, CW(vslot), vblk);
    };

    // weight prep + percentile thresholds (one launch)
    prep_percentile_kernel<<<dim3(100 + NROWS), b256, 0, stream>>>(
        pa, wcvt, m_dist, m102, m103);

    // encoder + V-projection for the down mhpa
    encoder_vproj_kernel<<<gT, b256, 0, stream>>>(inputs, en_W, en_b, ben,
                                                  CW(CW_DOWN), vblk);

    // down block
    K1(down_r, 1, CW_MLP1W1, mlp1_b1);
    K2(CW_MLP1W2, mlp1_b2, ben, CW_W1, w1_b, bx0, CW_PA + 0);

    // 4 processor blocks (ping-pong bx0/bx1)
    float* xin = bx0;
    float* xout = bx1;
    for (int i = 0; i < 4; ++i) {
        K1(pa_r + (size_t)i * NH, 0, CW_BLKW1 + i, blk_b1 + (size_t)i * HIDD);
        K2(CW_BLKW2 + i, blk_b2 + (size_t)i * HIDD,
           xin, CW_WI + i, wi_b + (size_t)i * HIDD,
           xout, (i < 3) ? (CW_PA + i + 1) : CW_UP);
        float* tmp = xin; xin = xout; xout = tmp;
    }
    // xin now holds x

    // up block + decoder + final (terminal fused kernel)
    K1(up_r, 1, CW_MLP2W1, mlp2_b1);
    mm2_decoder_kernel<<<gT, b256, 0, stream>>>(
        bt, CW(CW_MLP2W2), mlp2_b2,
        xin, CW(CW_W2), w2_b,
        CW(CW_DE1), de_b1, de_W2, de_b2, out);
}